// Round 1
// baseline (436.158 us; speedup 1.0000x reference)
//
#include <hip/hip_runtime.h>

// Problem constants
#define DIM   180
#define HEADS 6
#define HD    30
#define NKEY  144
#define NGS   2304
#define BATCH 64
#define TQ    64
#define QT    36                // q-tiles (2304/64)
#define WPAD  192               // padded model dim (6 k-tiles of 32)
#define SXS   200               // sXQ row stride u16 (400 B = 25*16, rows 16B-aligned)
#define KROW  40                // Kb row stride u16 (80 B, 16B-aligned)
#define VROW  144               // VbT row stride u16 (288 B, 16B-aligned)
#define KB_STRIDE (NKEY * KROW) // 5760 u16 per (b,h)
#define VB_STRIDE (32 * VROW)   // 4608 u16 per (b,h)

typedef unsigned short u16;
typedef short v8s __attribute__((ext_vector_type(8)));   // 8 x bf16 MFMA operand
typedef float v4f __attribute__((ext_vector_type(4)));   // 4 x f32 MFMA acc

__device__ __forceinline__ float bf2f(u16 u) {
    union { unsigned int i; float f; } w; w.i = ((unsigned int)u) << 16; return w.f;
}
__device__ __forceinline__ u16 f2bf(float f) {
    union { float f; unsigned int i; } w; w.f = f;
    unsigned int r = w.i + 0x7fffu + ((w.i >> 16) & 1u);
    return (u16)(r >> 16);
}
__device__ __forceinline__ uint2 pack4(const v4f& x) {
    uint2 r;
    r.x = (unsigned)f2bf(x[0]) | ((unsigned)f2bf(x[1]) << 16);
    r.y = (unsigned)f2bf(x[2]) | ((unsigned)f2bf(x[3]) << 16);
    return r;
}

// ---------------------------------------------------------------------------
// KEY PERMUTATION (R3): within every 16-key block of the S^T tile, C-row
// positions hold keys sigma = [0-3, 8-11, 4-7, 12-15] (groups 1<->2 swapped).
// With this order, the quad-transpose of P needed between softmax and PV is
// EXACTLY swap(lane-bit5, reg-bit) = one v_permlane32_swap_b32 per dword
// pair -> sP (19456 B of LDS) is eliminated entirely.
// sigma is applied to Kb rows (kv_proj) and biasCT rows (gather); VbT keeps
// natural key order (PV k-dim consumes keys in natural order).
// ---------------------------------------------------------------------------

// Weight prep: WqT[j][k] = Wq[k][j]; WpT[j][k'] with k' = h*32+dd (32-padded
// head-slab k-layout matching where attn leaves x in LDS), k = h*30+dd.
__global__ __launch_bounds__(256) void wt_prep_kernel(
    const float* __restrict__ Wq, const float* __restrict__ Wp,
    u16* __restrict__ WqT, u16* __restrict__ WpT) {
    int idx = blockIdx.x * 256 + threadIdx.x;        // < 2*192*192
    int sel = idx >= WPAD * WPAD;
    int rr  = sel ? idx - WPAD * WPAD : idx;
    int j = rr / WPAD, k = rr - j * WPAD;
    float v;
    if (!sel) {
        v = (j < DIM && k < DIM) ? Wq[k * DIM + j] : 0.f;
        WqT[j * WPAD + k] = f2bf(v);
    } else {
        int h = k >> 5, dd = k & 31;
        v = (j < DIM && dd < HD) ? Wp[(h * HD + dd) * DIM + j] : 0.f;
        WpT[j * WPAD + k] = f2bf(v);
    }
}

// ---------------------------------------------------------------------------
// Bias pre-gather in S^T C-fragment order WITH key permutation sigma: tile
// (h, g=q/16, t=n/16); lane (l15,quad) holds C-rows 16t+quad*4+r which carry
// keys 16t + pg*4 + r, pg = bit-reversed quad (0,2,1,3). col q=16g+l15.
__global__ __launch_bounds__(256) void gather_bias_kernel(
    const float* __restrict__ table, const int* __restrict__ rpi,
    u16* __restrict__ biasCT) {
    int i = blockIdx.x * 256 + threadIdx.x;          // < 7776*64 = 497664
    int lane = i & 63;
    int tile = i >> 6;
    int t = tile % 9;
    int rem = tile / 9;
    int g = rem % 144;
    int h = rem / 144;
    int qd = (lane >> 4) & 3;
    int pg = ((qd & 1) << 1) | (qd >> 1);            // sigma group: 0,2,1,3
    int q  = 16 * g + (lane & 15);
    int n0 = 16 * t + pg * 4;
    const int4 rr = *(const int4*)&rpi[q * NKEY + n0];
    unsigned lo = (unsigned)f2bf(table[rr.x * HEADS + h]) |
                  ((unsigned)f2bf(table[rr.y * HEADS + h]) << 16);
    unsigned hi = (unsigned)f2bf(table[rr.z * HEADS + h]) |
                  ((unsigned)f2bf(table[rr.w * HEADS + h]) << 16);
    ((uint2*)biasCT)[i] = make_uint2(lo, hi);
}

// ---------------------------------------------------------------------------
// K/V projection -> bf16 fragment-ready global layouts:
//   Kb [b][h][n'][40]  (row n' = sigma^-1(n); d pad 30..39 = 0 via memset)
//   VbT[b][h][d][144]  (natural key order; d rows 30,31 = 0 via memset)
__global__ __launch_bounds__(256) void kv_proj_kernel(
    const float* __restrict__ feat,
    const float* __restrict__ Wk, const float* __restrict__ bk,
    const float* __restrict__ Wv, const float* __restrict__ bv,
    u16* __restrict__ Kb, u16* __restrict__ VbT) {
    __shared__ float sF[16 * DIM];
    int b  = blockIdx.x / 9;
    int n0 = (blockIdx.x % 9) * 16;
    int tid = threadIdx.x;
    {
        const float4* src = (const float4*)(feat + (size_t)(b * NKEY + n0) * DIM);
        float4* dst = (float4*)sF;
        for (int i = tid; i < 16 * 45; i += 256) dst[i] = src[i];
    }
    __syncthreads();
    int j = tid;
    if (j < DIM) {
        float ak[16], av[16];
#pragma unroll
        for (int r = 0; r < 16; ++r) { ak[r] = 0.f; av[r] = 0.f; }
        const float4* sF4 = (const float4*)sF;
        for (int kc = 0; kc < 45; ++kc) {
            int kk = kc * 4;
            float wk0 = Wk[(kk + 0) * DIM + j], wk1 = Wk[(kk + 1) * DIM + j];
            float wk2 = Wk[(kk + 2) * DIM + j], wk3 = Wk[(kk + 3) * DIM + j];
            float wv0 = Wv[(kk + 0) * DIM + j], wv1 = Wv[(kk + 1) * DIM + j];
            float wv2 = Wv[(kk + 2) * DIM + j], wv3 = Wv[(kk + 3) * DIM + j];
#pragma unroll
            for (int r = 0; r < 16; ++r) {
                float4 g = sF4[r * 45 + kc];
                ak[r] = fmaf(g.x, wk0, ak[r]); ak[r] = fmaf(g.y, wk1, ak[r]);
                ak[r] = fmaf(g.z, wk2, ak[r]); ak[r] = fmaf(g.w, wk3, ak[r]);
                av[r] = fmaf(g.x, wv0, av[r]); av[r] = fmaf(g.y, wv1, av[r]);
                av[r] = fmaf(g.z, wv2, av[r]); av[r] = fmaf(g.w, wv3, av[r]);
            }
        }
        int h = j / HD, d = j - HD * h;
        u16* kp = Kb  + (size_t)(b * HEADS + h) * KB_STRIDE;
        u16* vp = VbT + (size_t)(b * HEADS + h) * VB_STRIDE;
        float bkj = bk[j], bvj = bv[j];
#pragma unroll
        for (int r = 0; r < 16; ++r) {
            // key n0+r lands at row position n0+sr (sigma involution)
            int sr = ((r >> 2) == 1) ? r + 4 : ((r >> 2) == 2) ? r - 4 : r;
            kp[(n0 + sr) * KROW + d] = f2bf(ak[r] + bkj);
            vp[d * VROW + n0 + r]    = f2bf(av[r] + bvj);
        }
    }
}

// ---------------------------------------------------------------------------
// Fused MFMA attention. One block = (batch, 64-query tile), 4 waves.
// LDS: sXQ only = 25600 B -> 6 blocks/CU (24 waves/CU), vs 3 with sP (R3).
// Head loop is BARRIER-FREE: K/V/bias fragments come straight from global
// (L2-resident); P lives ENTIRELY in registers — the quad transpose between
// softmax and PV is done by v_permlane32_swap_b32 (key order sigma makes the
// exchange exactly swap(lane-bit5, reg-bit)). NaN-hygiene: every MFMA
// operand is written data, explicit zeros, or a zero register.
__global__ __launch_bounds__(256, 6) void attn_kernel(
    const float* __restrict__ gs,
    const u16* __restrict__ WqT, const float* __restrict__ bq,
    const u16* __restrict__ WpT, const float* __restrict__ bp,
    const u16* __restrict__ Kb, const u16* __restrict__ VbT,
    const u16* __restrict__ biasCT, float* __restrict__ out) {

    __shared__ u16 sXQ[TQ * SXS];  // gs tile -> Q (head-slab layout) -> x

    const int tid  = threadIdx.x;
    const int w    = tid >> 6;        // wave 0..3
    const int lane = tid & 63;
    const int l15  = tid & 15;
    const int quad = (tid >> 4) & 3;
    const int b    = blockIdx.x / QT;
    const int qt   = blockIdx.x % QT;
    const int q0   = qt * TQ;
    const float SCALE = 0.18257418583505536f;   // 1/sqrt(30)

    // ---- stage gs tile -> sXQ (bf16, zero pad cols 180..195) ----
    {
        const float4* src = (const float4*)(gs + (size_t)(b * NGS + q0) * DIM);
        for (int i = tid; i < TQ * 45; i += 256) {
            int row = i / 45, c = i - row * 45;
            float4 g = src[row * 45 + c];
            unsigned lo = (unsigned)f2bf(g.x) | ((unsigned)f2bf(g.y) << 16);
            unsigned hi = (unsigned)f2bf(g.z) | ((unsigned)f2bf(g.w) << 16);
            *(uint2*)&sXQ[row * SXS + c * 4] = make_uint2(lo, hi);
        }
        for (int i = tid; i < TQ * 16; i += 256)
            sXQ[(i >> 4) * SXS + 180 + (i & 15)] = 0;
    }
    __syncthreads();

    // ---- Q-proj: q = (gs @ Wq + bq)*scale. Accumulate in regs, then
    //      overwrite the (dead) gs tile with Q in 32-padded head-slab cols.
    v4f qacc[12];
#pragma unroll
    for (int i = 0; i < 12; ++i) qacc[i] = (v4f){0.f, 0.f, 0.f, 0.f};
    for (int kt = 0; kt < 6; ++kt) {
        v8s A[4];
#pragma unroll
        for (int m = 0; m < 4; ++m)
            A[m] = *(const v8s*)&sXQ[(16 * m + l15) * SXS + kt * 32 + quad * 8];
#pragma unroll
        for (int jj = 0; jj < 3; ++jj) {
            v8s B = *(const v8s*)&WqT[(size_t)((3 * w + jj) * 16 + l15) * WPAD +
                                      kt * 32 + quad * 8];
#pragma unroll
            for (int m = 0; m < 4; ++m)
                qacc[jj * 4 + m] = __builtin_amdgcn_mfma_f32_16x16x32_bf16(
                    A[m], B, qacc[jj * 4 + m], 0, 0, 0);
        }
    }
    __syncthreads();   // all waves done READING gs before Q overwrites it
#pragma unroll
    for (int jj = 0; jj < 3; ++jj) {
        int j = (3 * w + jj) * 16 + l15;
        if (j < DIM) {
            int h = j / HD;
            int pos = j + 2 * h;          // 32-padded head-slab column
            float bqj = bq[j];
#pragma unroll
            for (int m = 0; m < 4; ++m)
#pragma unroll
                for (int r = 0; r < 4; ++r)
                    sXQ[(16 * m + quad * 4 + r) * SXS + pos] =
                        f2bf((qacc[jj * 4 + m][r] + bqj) * SCALE);
        }
    }
    // zero Q pad cols d=30,31 of every head slab
    for (int i = tid; i < TQ * 12; i += 256) {
        int row = i / 12, c = i - row * 12;
        sXQ[row * SXS + (c >> 1) * 32 + 30 + (c & 1)] = 0;
    }
    __syncthreads();

    // ---- per-head attention (no barriers inside) ----
    for (int h = 0; h < HEADS; ++h) {
        const u16* kp = Kb  + (size_t)(b * HEADS + h) * KB_STRIDE;
        const u16* vp = VbT + (size_t)(b * HEADS + h) * VB_STRIDE;

        // Q B-fragment: own q rows (16w+l15), this head's 32-col slab
        v8s qa = *(const v8s*)&sXQ[(16 * w + l15) * SXS + h * 32 + quad * 8];

        // S^T = K · Q^T + bias^T : A = K rows (permuted keys), B = Q.
        // C tile t: rowpos n'=16t+quad*4+r (key sigma(n')), col q=16w+l15.
        v4f la[9];
        const u16* bgt = biasCT +
            ((size_t)((h * 144 + (qt * 4 + w)) * 9) * 256) + lane * 4;
#pragma unroll
        for (int t = 0; t < 9; ++t) {
            uint2 bb = *(const uint2*)(bgt + t * 256);
            v4f c;
            c[0] = bf2f((u16)(bb.x & 0xffff));
            c[1] = bf2f((u16)(bb.x >> 16));
            c[2] = bf2f((u16)(bb.y & 0xffff));
            c[3] = bf2f((u16)(bb.y >> 16));
            v8s kb = *(const v8s*)&kp[(16 * t + l15) * KROW + quad * 8];
            la[t] = __builtin_amdgcn_mfma_f32_16x16x32_bf16(kb, qa, c, 0, 0, 0);
        }

        // softmax: all 36 values in this lane share q = 16w+l15; quads hold
        // disjoint keys -> reduce across quads with xor 16,32 only.
        // (key order is permuted, but max/sum are order-invariant)
        float m = la[0][0];
#pragma unroll
        for (int t = 0; t < 9; ++t)
#pragma unroll
            for (int r = 0; r < 4; ++r) m = fmaxf(m, la[t][r]);
        m = fmaxf(m, __shfl_xor(m, 16));
        m = fmaxf(m, __shfl_xor(m, 32));
        float s = 0.f;
#pragma unroll
        for (int t = 0; t < 9; ++t)
#pragma unroll
            for (int r = 0; r < 4; ++r) {
                la[t][r] = __expf(la[t][r] - m);
                s += la[t][r];
            }
        s += __shfl_xor(s, 16);
        s += __shfl_xor(s, 32);
        float inv = 1.f / s;

        // pack P rows to bf16 dwords: sd0[t]=keys(rowpos 4q+0,1),
        // sd1[t]=keys(rowpos 4q+2,3) of tile t, scaled by inv.
        unsigned sd0[9], sd1[9];
#pragma unroll
        for (int t = 0; t < 9; ++t) {
            sd0[t] = (unsigned)f2bf(la[t][0] * inv) |
                     ((unsigned)f2bf(la[t][1] * inv) << 16);
            sd1[t] = (unsigned)f2bf(la[t][2] * inv) |
                     ((unsigned)f2bf(la[t][3] * inv) << 16);
        }

        // x^T = V^T · P^T : A = V^T rows (lane=d), B = P^T (lane=q col).
        // B-fragment (8 contiguous keys per lane) is produced IN-REGISTER:
        // thanks to sigma, dest(lane-b5, reg) = src(reg, lane-b5), which is
        // exactly v_permlane32_swap_b32 on dword pairs. kt=4 swaps against
        // zero regs -> keys 144..159 are zero (no sP, no LDS round-trip).
        v4f x0 = (v4f){0.f, 0.f, 0.f, 0.f}, x1 = x0;
#pragma unroll
        for (int kt = 0; kt < 5; ++kt) {
            unsigned d0, d1, d2, d3;
            if (kt < 4) {
                d0 = sd0[2 * kt];     d1 = sd1[2 * kt];
                d2 = sd0[2 * kt + 1]; d3 = sd1[2 * kt + 1];
            } else {
                d0 = sd0[8]; d1 = sd1[8]; d2 = 0u; d3 = 0u;
            }
            asm("v_permlane32_swap_b32 %0, %1" : "+v"(d0), "+v"(d2));
            asm("v_permlane32_swap_b32 %0, %1" : "+v"(d1), "+v"(d3));
            union { unsigned u[4]; v8s v; } pu;
            pu.u[0] = d0; pu.u[1] = d1; pu.u[2] = d2; pu.u[3] = d3;
            int co = kt * 32 + quad * 8;
            co = (co < NKEY) ? co : 0;       // pa is zero there (kt=4,q>=2)
            v8s a0 = *(const v8s*)&vp[l15 * VROW + co];
            v8s a1 = *(const v8s*)&vp[(16 + l15) * VROW + co];
            x0 = __builtin_amdgcn_mfma_f32_16x16x32_bf16(a0, pu.v, x0, 0, 0, 0);
            x1 = __builtin_amdgcn_mfma_f32_16x16x32_bf16(a1, pu.v, x1, 0, 0, 0);
        }
        // x^T C tile: row d=quad*4+r (tile0) / 16+quad*4+r (tile1), col q=l15.
        // Write x[q][h*32+d] into the dead Q slab h; d=30,31 are zero because
        // VbT rows 30,31 are zero. 4 consecutive cols -> ds_write_b64.
        *(uint2*)&sXQ[(16 * w + l15) * SXS + h * 32 + quad * 4]      = pack4(x0);
        *(uint2*)&sXQ[(16 * w + l15) * SXS + h * 32 + 16 + quad * 4] = pack4(x1);
    }
    __syncthreads();   // x rows are read cross-wave by out-proj

    // ---- out-proj: out = x @ Wp + bp (WpT is in matching 32-padded k-layout)
    {
        v4f acc[12];
#pragma unroll
        for (int i = 0; i < 12; ++i) acc[i] = (v4f){0.f, 0.f, 0.f, 0.f};
        for (int kt = 0; kt < 6; ++kt) {
            v8s A[4];
#pragma unroll
            for (int m = 0; m < 4; ++m)
                A[m] = *(const v8s*)&sXQ[(16 * m + l15) * SXS + kt * 32 + quad * 8];
#pragma unroll
            for (int jj = 0; jj < 3; ++jj) {
                v8s B = *(const v8s*)&WpT[(size_t)((3 * w + jj) * 16 + l15) * WPAD +
                                          kt * 32 + quad * 8];
#pragma unroll
                for (int m = 0; m < 4; ++m)
                    acc[jj * 4 + m] = __builtin_amdgcn_mfma_f32_16x16x32_bf16(
                        A[m], B, acc[jj * 4 + m], 0, 0, 0);
            }
        }
#pragma unroll
        for (int jj = 0; jj < 3; ++jj) {
            int j = (3 * w + jj) * 16 + l15;
            if (j < DIM) {
                float bpj = bp[j];
#pragma unroll
                for (int m = 0; m < 4; ++m)
#pragma unroll
                    for (int r = 0; r < 4; ++r)
                        out[(size_t)(b * NGS + q0 + 16 * m + quad * 4 + r) * DIM + j] =
                            acc[jj * 4 + m][r] + bpj;
            }
        }
    }
}

// ---------------------------------------------------------------------------
extern "C" void kernel_launch(void* const* d_in, const int* in_sizes, int n_in,
                              void* d_out, int out_size, void* d_ws, size_t ws_size,
                              hipStream_t stream) {
    const float* gs    = (const float*)d_in[0];
    const float* feat  = (const float*)d_in[1];
    const float* Wq    = (const float*)d_in[2];
    const float* bq    = (const float*)d_in[3];
    const float* Wk    = (const float*)d_in[4];
    const float* bk    = (const float*)d_in[5];
    const float* Wv    = (const float*)d_in[6];
    const float* bv    = (const float*)d_in[7];
    const float* Wp    = (const float*)d_in[8];
    const float* bp    = (const float*)d_in[9];
    const float* table = (const float*)d_in[10];
    const int*   rpi   = (const int*)d_in[11];
    float* out = (float*)d_out;

    // ws layout (u16 units): WqT | WpT | Kb | VbT | biasCT  (~12.1 MB)
    u16* WqT    = (u16*)d_ws;
    u16* WpT    = WqT + WPAD * WPAD;
    u16* Kb     = WpT + WPAD * WPAD;
    u16* VbT    = Kb  + (size_t)BATCH * HEADS * KB_STRIDE;
    u16* biasCT = VbT + (size_t)BATCH * HEADS * VB_STRIDE;

    // zero K pads (d=30..39) and V pad rows (d=30,31): MFMA reads them
    size_t zero_bytes = (size_t)BATCH * HEADS * (KB_STRIDE + VB_STRIDE) * sizeof(u16);
    hipMemsetAsync(Kb, 0, zero_bytes, stream);

    wt_prep_kernel<<<dim3(2 * WPAD * WPAD / 256), dim3(256), 0, stream>>>(Wq, Wp, WqT, WpT);
    gather_bias_kernel<<<dim3(HEADS * 144 * 9 * 64 / 256), dim3(256), 0, stream>>>(
        table, rpi, biasCT);
    kv_proj_kernel<<<dim3(BATCH * 9), dim3(256), 0, stream>>>(feat, Wk, bk, Wv, bv, Kb, VbT);
    attn_kernel<<<dim3(BATCH * QT), dim3(256), 0, stream>>>(
        gs, WqT, bq, WpT, bp, Kb, VbT, biasCT, out);
}

// Round 2
// 435.219 us; speedup vs baseline: 1.0022x; 1.0022x over previous
//
#include <hip/hip_runtime.h>

// Problem constants
#define DIM   180
#define HEADS 6
#define HD    30
#define NKEY  144
#define NGS   2304
#define BATCH 64
#define TQ    64
#define QT    36                // q-tiles (2304/64)
#define WPAD  192               // padded model dim (6 k-tiles of 32)
#define SXS   200               // sXQ row stride u16 (400 B = 25*16, rows 16B-aligned)
#define KROW  40                // Kb row stride u16 (80 B, 16B-aligned)
#define VROW  144               // VbT row stride u16 (288 B, 16B-aligned)
#define KB_STRIDE (NKEY * KROW) // 5760 u16 per (b,h)
#define VB_STRIDE (32 * VROW)   // 4608 u16 per (b,h)

typedef unsigned short u16;
typedef short v8s __attribute__((ext_vector_type(8)));   // 8 x bf16 MFMA operand
typedef float v4f __attribute__((ext_vector_type(4)));   // 4 x f32 MFMA acc

__device__ __forceinline__ float bf2f(u16 u) {
    union { unsigned int i; float f; } w; w.i = ((unsigned int)u) << 16; return w.f;
}
__device__ __forceinline__ u16 f2bf(float f) {
    union { float f; unsigned int i; } w; w.f = f;
    unsigned int r = w.i + 0x7fffu + ((w.i >> 16) & 1u);
    return (u16)(r >> 16);
}
__device__ __forceinline__ uint2 pack4(const v4f& x) {
    uint2 r;
    r.x = (unsigned)f2bf(x[0]) | ((unsigned)f2bf(x[1]) << 16);
    r.y = (unsigned)f2bf(x[2]) | ((unsigned)f2bf(x[3]) << 16);
    return r;
}

// ---------------------------------------------------------------------------
// KEY PERMUTATION (R1): within every 16-key block of the S^T tile, C-row
// positions hold keys sigma = [0-3, 8-11, 4-7, 12-15] (groups 1<->2 swapped).
// With this order, the quad-transpose of P needed between softmax and PV is
// EXACTLY swap(lane-bit5, reg-bit) = one v_permlane32_swap_b32 per dword
// pair -> sP eliminated, P lives entirely in registers.
// R2: epilogue writes were cross-wave partial 128B lines -> at 6 blocks/CU
// L2 evicted half-assembled lines (WRITE_SIZE 242MB for a 106MB output).
// Fix: stage the 64x180 f32 out tile in (dead) sXQ, store fully coalesced.
// ---------------------------------------------------------------------------

// Weight prep: WqT[j][k] = Wq[k][j]; WpT[j][k'] with k' = h*32+dd (32-padded
// head-slab k-layout matching where attn leaves x in LDS), k = h*30+dd.
__global__ __launch_bounds__(256) void wt_prep_kernel(
    const float* __restrict__ Wq, const float* __restrict__ Wp,
    u16* __restrict__ WqT, u16* __restrict__ WpT) {
    int idx = blockIdx.x * 256 + threadIdx.x;        // < 2*192*192
    int sel = idx >= WPAD * WPAD;
    int rr  = sel ? idx - WPAD * WPAD : idx;
    int j = rr / WPAD, k = rr - j * WPAD;
    float v;
    if (!sel) {
        v = (j < DIM && k < DIM) ? Wq[k * DIM + j] : 0.f;
        WqT[j * WPAD + k] = f2bf(v);
    } else {
        int h = k >> 5, dd = k & 31;
        v = (j < DIM && dd < HD) ? Wp[(h * HD + dd) * DIM + j] : 0.f;
        WpT[j * WPAD + k] = f2bf(v);
    }
}

// ---------------------------------------------------------------------------
// Bias pre-gather in S^T C-fragment order WITH key permutation sigma: tile
// (h, g=q/16, t=n/16); lane (l15,quad) holds C-rows 16t+quad*4+r which carry
// keys 16t + pg*4 + r, pg = bit-reversed quad (0,2,1,3). col q=16g+l15.
__global__ __launch_bounds__(256) void gather_bias_kernel(
    const float* __restrict__ table, const int* __restrict__ rpi,
    u16* __restrict__ biasCT) {
    int i = blockIdx.x * 256 + threadIdx.x;          // < 7776*64 = 497664
    int lane = i & 63;
    int tile = i >> 6;
    int t = tile % 9;
    int rem = tile / 9;
    int g = rem % 144;
    int h = rem / 144;
    int qd = (lane >> 4) & 3;
    int pg = ((qd & 1) << 1) | (qd >> 1);            // sigma group: 0,2,1,3
    int q  = 16 * g + (lane & 15);
    int n0 = 16 * t + pg * 4;
    const int4 rr = *(const int4*)&rpi[q * NKEY + n0];
    unsigned lo = (unsigned)f2bf(table[rr.x * HEADS + h]) |
                  ((unsigned)f2bf(table[rr.y * HEADS + h]) << 16);
    unsigned hi = (unsigned)f2bf(table[rr.z * HEADS + h]) |
                  ((unsigned)f2bf(table[rr.w * HEADS + h]) << 16);
    ((uint2*)biasCT)[i] = make_uint2(lo, hi);
}

// ---------------------------------------------------------------------------
// K/V projection -> bf16 fragment-ready global layouts:
//   Kb [b][h][n'][40]  (row n' = sigma^-1(n); d pad 30..39 = 0 via memset)
//   VbT[b][h][d][144]  (natural key order; d rows 30,31 = 0 via memset)
__global__ __launch_bounds__(256) void kv_proj_kernel(
    const float* __restrict__ feat,
    const float* __restrict__ Wk, const float* __restrict__ bk,
    const float* __restrict__ Wv, const float* __restrict__ bv,
    u16* __restrict__ Kb, u16* __restrict__ VbT) {
    __shared__ float sF[16 * DIM];
    int b  = blockIdx.x / 9;
    int n0 = (blockIdx.x % 9) * 16;
    int tid = threadIdx.x;
    {
        const float4* src = (const float4*)(feat + (size_t)(b * NKEY + n0) * DIM);
        float4* dst = (float4*)sF;
        for (int i = tid; i < 16 * 45; i += 256) dst[i] = src[i];
    }
    __syncthreads();
    int j = tid;
    if (j < DIM) {
        float ak[16], av[16];
#pragma unroll
        for (int r = 0; r < 16; ++r) { ak[r] = 0.f; av[r] = 0.f; }
        const float4* sF4 = (const float4*)sF;
        for (int kc = 0; kc < 45; ++kc) {
            int kk = kc * 4;
            float wk0 = Wk[(kk + 0) * DIM + j], wk1 = Wk[(kk + 1) * DIM + j];
            float wk2 = Wk[(kk + 2) * DIM + j], wk3 = Wk[(kk + 3) * DIM + j];
            float wv0 = Wv[(kk + 0) * DIM + j], wv1 = Wv[(kk + 1) * DIM + j];
            float wv2 = Wv[(kk + 2) * DIM + j], wv3 = Wv[(kk + 3) * DIM + j];
#pragma unroll
            for (int r = 0; r < 16; ++r) {
                float4 g = sF4[r * 45 + kc];
                ak[r] = fmaf(g.x, wk0, ak[r]); ak[r] = fmaf(g.y, wk1, ak[r]);
                ak[r] = fmaf(g.z, wk2, ak[r]); ak[r] = fmaf(g.w, wk3, ak[r]);
                av[r] = fmaf(g.x, wv0, av[r]); av[r] = fmaf(g.y, wv1, av[r]);
                av[r] = fmaf(g.z, wv2, av[r]); av[r] = fmaf(g.w, wv3, av[r]);
            }
        }
        int h = j / HD, d = j - HD * h;
        u16* kp = Kb  + (size_t)(b * HEADS + h) * KB_STRIDE;
        u16* vp = VbT + (size_t)(b * HEADS + h) * VB_STRIDE;
        float bkj = bk[j], bvj = bv[j];
#pragma unroll
        for (int r = 0; r < 16; ++r) {
            // key n0+r lands at row position n0+sr (sigma involution)
            int sr = ((r >> 2) == 1) ? r + 4 : ((r >> 2) == 2) ? r - 4 : r;
            kp[(n0 + sr) * KROW + d] = f2bf(ak[r] + bkj);
            vp[d * VROW + n0 + r]    = f2bf(av[r] + bvj);
        }
    }
}

// ---------------------------------------------------------------------------
// Fused MFMA attention. One block = (batch, 64-query tile), 4 waves.
// LDS: sXQ only = 25600 B -> 6 blocks/CU (24 waves/CU).
// Head loop is BARRIER-FREE: K/V/bias fragments come straight from global
// (L2/L3-resident); P lives entirely in registers (permlane32_swap quad
// transpose, enabled by key-order sigma). R2: XCD-swizzled blockIdx (blocks
// on one XCD share b -> K/V working set ~1MB/XCD-L2) and LDS-staged fully
// coalesced f32 epilogue (single-wave full-line stores; no cross-wave
// partial-line assembly in L2).
__global__ __launch_bounds__(256, 6) void attn_kernel(
    const float* __restrict__ gs,
    const u16* __restrict__ WqT, const float* __restrict__ bq,
    const u16* __restrict__ WpT, const float* __restrict__ bp,
    const u16* __restrict__ Kb, const u16* __restrict__ VbT,
    const u16* __restrict__ biasCT, float* __restrict__ out) {

    __shared__ __align__(16) u16 sXQ[TQ * SXS]; // gs -> Q -> x -> f32 out tile

    const int tid  = threadIdx.x;
    const int w    = tid >> 6;        // wave 0..3
    const int lane = tid & 63;
    const int l15  = tid & 15;
    const int quad = (tid >> 4) & 3;
    // bijective XCD swizzle: 2304 blocks, 8 XCDs, 288/XCD contiguous chunk.
    // Concurrent blocks on an XCD then share b (K/V L2 locality).
    const int bid  = blockIdx.x;
    const int swz  = (bid & 7) * (BATCH * QT / 8) + (bid >> 3);
    const int b    = swz / QT;
    const int qt   = swz - b * QT;
    const int q0   = qt * TQ;
    const float SCALE = 0.18257418583505536f;   // 1/sqrt(30)

    // ---- stage gs tile -> sXQ (bf16, zero pad cols 180..195) ----
    {
        const float4* src = (const float4*)(gs + (size_t)(b * NGS + q0) * DIM);
        for (int i = tid; i < TQ * 45; i += 256) {
            int row = i / 45, c = i - row * 45;
            float4 g = src[row * 45 + c];
            unsigned lo = (unsigned)f2bf(g.x) | ((unsigned)f2bf(g.y) << 16);
            unsigned hi = (unsigned)f2bf(g.z) | ((unsigned)f2bf(g.w) << 16);
            *(uint2*)&sXQ[row * SXS + c * 4] = make_uint2(lo, hi);
        }
        for (int i = tid; i < TQ * 16; i += 256)
            sXQ[(i >> 4) * SXS + 180 + (i & 15)] = 0;
    }
    __syncthreads();

    // ---- Q-proj: q = (gs @ Wq + bq)*scale. Accumulate in regs, then
    //      overwrite the (dead) gs tile with Q in 32-padded head-slab cols.
    v4f qacc[12];
#pragma unroll
    for (int i = 0; i < 12; ++i) qacc[i] = (v4f){0.f, 0.f, 0.f, 0.f};
    for (int kt = 0; kt < 6; ++kt) {
        v8s A[4];
#pragma unroll
        for (int m = 0; m < 4; ++m)
            A[m] = *(const v8s*)&sXQ[(16 * m + l15) * SXS + kt * 32 + quad * 8];
#pragma unroll
        for (int jj = 0; jj < 3; ++jj) {
            v8s B = *(const v8s*)&WqT[(size_t)((3 * w + jj) * 16 + l15) * WPAD +
                                      kt * 32 + quad * 8];
#pragma unroll
            for (int m = 0; m < 4; ++m)
                qacc[jj * 4 + m] = __builtin_amdgcn_mfma_f32_16x16x32_bf16(
                    A[m], B, qacc[jj * 4 + m], 0, 0, 0);
        }
    }
    __syncthreads();   // all waves done READING gs before Q overwrites it
#pragma unroll
    for (int jj = 0; jj < 3; ++jj) {
        int j = (3 * w + jj) * 16 + l15;
        if (j < DIM) {
            int h = j / HD;
            int pos = j + 2 * h;          // 32-padded head-slab column
            float bqj = bq[j];
#pragma unroll
            for (int m = 0; m < 4; ++m)
#pragma unroll
                for (int r = 0; r < 4; ++r)
                    sXQ[(16 * m + quad * 4 + r) * SXS + pos] =
                        f2bf((qacc[jj * 4 + m][r] + bqj) * SCALE);
        }
    }
    // zero Q pad cols d=30,31 of every head slab
    for (int i = tid; i < TQ * 12; i += 256) {
        int row = i / 12, c = i - row * 12;
        sXQ[row * SXS + (c >> 1) * 32 + 30 + (c & 1)] = 0;
    }
    __syncthreads();

    // ---- per-head attention (no barriers inside) ----
    for (int h = 0; h < HEADS; ++h) {
        const u16* kp = Kb  + (size_t)(b * HEADS + h) * KB_STRIDE;
        const u16* vp = VbT + (size_t)(b * HEADS + h) * VB_STRIDE;

        // Q B-fragment: own q rows (16w+l15), this head's 32-col slab
        v8s qa = *(const v8s*)&sXQ[(16 * w + l15) * SXS + h * 32 + quad * 8];

        // S^T = K · Q^T + bias^T : A = K rows (permuted keys), B = Q.
        // C tile t: rowpos n'=16t+quad*4+r (key sigma(n')), col q=16w+l15.
        v4f la[9];
        const u16* bgt = biasCT +
            ((size_t)((h * 144 + (qt * 4 + w)) * 9) * 256) + lane * 4;
#pragma unroll
        for (int t = 0; t < 9; ++t) {
            uint2 bb = *(const uint2*)(bgt + t * 256);
            v4f c;
            c[0] = bf2f((u16)(bb.x & 0xffff));
            c[1] = bf2f((u16)(bb.x >> 16));
            c[2] = bf2f((u16)(bb.y & 0xffff));
            c[3] = bf2f((u16)(bb.y >> 16));
            v8s kb = *(const v8s*)&kp[(16 * t + l15) * KROW + quad * 8];
            la[t] = __builtin_amdgcn_mfma_f32_16x16x32_bf16(kb, qa, c, 0, 0, 0);
        }

        // softmax: all 36 values in this lane share q = 16w+l15; quads hold
        // disjoint keys -> reduce across quads with xor 16,32 only.
        float m = la[0][0];
#pragma unroll
        for (int t = 0; t < 9; ++t)
#pragma unroll
            for (int r = 0; r < 4; ++r) m = fmaxf(m, la[t][r]);
        m = fmaxf(m, __shfl_xor(m, 16));
        m = fmaxf(m, __shfl_xor(m, 32));
        float s = 0.f;
#pragma unroll
        for (int t = 0; t < 9; ++t)
#pragma unroll
            for (int r = 0; r < 4; ++r) {
                la[t][r] = __expf(la[t][r] - m);
                s += la[t][r];
            }
        s += __shfl_xor(s, 16);
        s += __shfl_xor(s, 32);
        float inv = 1.f / s;

        // pack P rows to bf16 dwords: sd0[t]=keys(rowpos 4q+0,1),
        // sd1[t]=keys(rowpos 4q+2,3) of tile t, scaled by inv.
        unsigned sd0[9], sd1[9];
#pragma unroll
        for (int t = 0; t < 9; ++t) {
            sd0[t] = (unsigned)f2bf(la[t][0] * inv) |
                     ((unsigned)f2bf(la[t][1] * inv) << 16);
            sd1[t] = (unsigned)f2bf(la[t][2] * inv) |
                     ((unsigned)f2bf(la[t][3] * inv) << 16);
        }

        // x^T = V^T · P^T : A = V^T rows (lane=d), B = P^T (lane=q col).
        // B-fragment (8 contiguous keys per lane) is produced IN-REGISTER:
        // thanks to sigma, dest(lane-b5, reg) = src(reg, lane-b5), which is
        // exactly v_permlane32_swap_b32 on dword pairs. kt=4 swaps against
        // zero regs -> keys 144..159 are zero.
        v4f x0 = (v4f){0.f, 0.f, 0.f, 0.f}, x1 = x0;
#pragma unroll
        for (int kt = 0; kt < 5; ++kt) {
            unsigned d0, d1, d2, d3;
            if (kt < 4) {
                d0 = sd0[2 * kt];     d1 = sd1[2 * kt];
                d2 = sd0[2 * kt + 1]; d3 = sd1[2 * kt + 1];
            } else {
                d0 = sd0[8]; d1 = sd1[8]; d2 = 0u; d3 = 0u;
            }
            asm("v_permlane32_swap_b32 %0, %1" : "+v"(d0), "+v"(d2));
            asm("v_permlane32_swap_b32 %0, %1" : "+v"(d1), "+v"(d3));
            union { unsigned u[4]; v8s v; } pu;
            pu.u[0] = d0; pu.u[1] = d1; pu.u[2] = d2; pu.u[3] = d3;
            int co = kt * 32 + quad * 8;
            co = (co < NKEY) ? co : 0;       // pa is zero there (kt=4,q>=2)
            v8s a0 = *(const v8s*)&vp[l15 * VROW + co];
            v8s a1 = *(const v8s*)&vp[(16 + l15) * VROW + co];
            x0 = __builtin_amdgcn_mfma_f32_16x16x32_bf16(a0, pu.v, x0, 0, 0, 0);
            x1 = __builtin_amdgcn_mfma_f32_16x16x32_bf16(a1, pu.v, x1, 0, 0, 0);
        }
        // x^T C tile: row d=quad*4+r (tile0) / 16+quad*4+r (tile1), col q=l15.
        // Write x[q][h*32+d] into the dead Q slab h; d=30,31 are zero because
        // VbT rows 30,31 are zero. 4 consecutive cols -> ds_write_b64.
        *(uint2*)&sXQ[(16 * w + l15) * SXS + h * 32 + quad * 4]      = pack4(x0);
        *(uint2*)&sXQ[(16 * w + l15) * SXS + h * 32 + 16 + quad * 4] = pack4(x1);
    }
    __syncthreads();   // x rows are read cross-wave by out-proj

    // ---- out-proj: out = x @ Wp + bp (WpT is in matching 32-padded k-layout)
    {
        v4f acc[12];
#pragma unroll
        for (int i = 0; i < 12; ++i) acc[i] = (v4f){0.f, 0.f, 0.f, 0.f};
        for (int kt = 0; kt < 6; ++kt) {
            v8s A[4];
#pragma unroll
            for (int m = 0; m < 4; ++m)
                A[m] = *(const v8s*)&sXQ[(16 * m + l15) * SXS + kt * 32 + quad * 8];
#pragma unroll
            for (int jj = 0; jj < 3; ++jj) {
                v8s B = *(const v8s*)&WpT[(size_t)((3 * w + jj) * 16 + l15) * WPAD +
                                          kt * 32 + quad * 8];
#pragma unroll
                for (int m = 0; m < 4; ++m)
                    acc[jj * 4 + m] = __builtin_amdgcn_mfma_f32_16x16x32_bf16(
                        A[m], B, acc[jj * 4 + m], 0, 0, 0);
            }
        }
        __syncthreads();   // all sXQ reads done; reuse it as f32 out staging

        // R2 epilogue: stage 32 rows (23040 B fits sXQ) then store the
        // block's CONTIGUOUS out tile with full-line float4 stores.
        float* sOutF = (float*)sXQ;
#pragma unroll
        for (int half = 0; half < 2; ++half) {
#pragma unroll
            for (int jj = 0; jj < 3; ++jj) {
                int j = (3 * w + jj) * 16 + l15;
                if (j < DIM) {
                    float bpj = bp[j];
#pragma unroll
                    for (int m = 0; m < 2; ++m) {        // local row group
                        int mm = half * 2 + m;           // acc row group
#pragma unroll
                        for (int r = 0; r < 4; ++r)
                            sOutF[(16 * m + quad * 4 + r) * DIM + j] =
                                acc[jj * 4 + mm][r] + bpj;
                    }
                }
            }
            __syncthreads();
            const float4* s4 = (const float4*)sOutF;
            float4* dst = (float4*)(out + (size_t)(b * NGS + q0 + 32 * half) * DIM);
            for (int i = tid; i < 32 * DIM / 4; i += 256) dst[i] = s4[i];
            if (half == 0) __syncthreads();  // staging reused by half 1
        }
    }
}

// ---------------------------------------------------------------------------
extern "C" void kernel_launch(void* const* d_in, const int* in_sizes, int n_in,
                              void* d_out, int out_size, void* d_ws, size_t ws_size,
                              hipStream_t stream) {
    const float* gs    = (const float*)d_in[0];
    const float* feat  = (const float*)d_in[1];
    const float* Wq    = (const float*)d_in[2];
    const float* bq    = (const float*)d_in[3];
    const float* Wk    = (const float*)d_in[4];
    const float* bk    = (const float*)d_in[5];
    const float* Wv    = (const float*)d_in[6];
    const float* bv    = (const float*)d_in[7];
    const float* Wp    = (const float*)d_in[8];
    const float* bp    = (const float*)d_in[9];
    const float* table = (const float*)d_in[10];
    const int*   rpi   = (const int*)d_in[11];
    float* out = (float*)d_out;

    // ws layout (u16 units): WqT | WpT | Kb | VbT | biasCT  (~12.1 MB)
    u16* WqT    = (u16*)d_ws;
    u16* WpT    = WqT + WPAD * WPAD;
    u16* Kb     = WpT + WPAD * WPAD;
    u16* VbT    = Kb  + (size_t)BATCH * HEADS * KB_STRIDE;
    u16* biasCT = VbT + (size_t)BATCH * HEADS * VB_STRIDE;

    // zero K pads (d=30..39) and V pad rows (d=30,31): MFMA reads them
    size_t zero_bytes = (size_t)BATCH * HEADS * (KB_STRIDE + VB_STRIDE) * sizeof(u16);
    hipMemsetAsync(Kb, 0, zero_bytes, stream);

    wt_prep_kernel<<<dim3(2 * WPAD * WPAD / 256), dim3(256), 0, stream>>>(Wq, Wp, WqT, WpT);
    gather_bias_kernel<<<dim3(HEADS * 144 * 9 * 64 / 256), dim3(256), 0, stream>>>(
        table, rpi, biasCT);
    kv_proj_kernel<<<dim3(BATCH * 9), dim3(256), 0, stream>>>(feat, Wk, bk, Wv, bv, Kb, VbT);
    attn_kernel<<<dim3(BATCH * QT), dim3(256), 0, stream>>>(
        gs, WqT, bq, WpT, bp, Kb, VbT, biasCT, out);
}

// Round 3
// 406.833 us; speedup vs baseline: 1.0721x; 1.0698x over previous
//
#include <hip/hip_runtime.h>

// Problem constants
#define DIM   180
#define HEADS 6
#define HD    30
#define NKEY  144
#define NGS   2304
#define BATCH 64
#define TQ    64
#define QT    36                // q-tiles (2304/64)
#define WPAD  192               // padded model dim (6 k-tiles of 32)
#define SXS   200               // sXQ row stride u16 (400 B = 25*16, rows 16B-aligned)
#define KROW  40                // Kb row stride u16 (80 B, 16B-aligned)
#define VROW  144               // VbT row stride u16 (288 B, 16B-aligned)
#define KB_STRIDE (NKEY * KROW) // 5760 u16 per (b,h)
#define VB_STRIDE (32 * VROW)   // 4608 u16 per (b,h)

typedef unsigned short u16;
typedef short v8s __attribute__((ext_vector_type(8)));   // 8 x bf16 MFMA operand
typedef float v4f __attribute__((ext_vector_type(4)));   // 4 x f32 MFMA acc

__device__ __forceinline__ float bf2f(u16 u) {
    union { unsigned int i; float f; } w; w.i = ((unsigned int)u) << 16; return w.f;
}
__device__ __forceinline__ u16 f2bf(float f) {
    union { float f; unsigned int i; } w; w.f = f;
    unsigned int r = w.i + 0x7fffu + ((w.i >> 16) & 1u);
    return (u16)(r >> 16);
}
__device__ __forceinline__ uint2 pack4(const v4f& x) {
    uint2 r;
    r.x = (unsigned)f2bf(x[0]) | ((unsigned)f2bf(x[1]) << 16);
    r.y = (unsigned)f2bf(x[2]) | ((unsigned)f2bf(x[3]) << 16);
    return r;
}

// ---------------------------------------------------------------------------
// KEY PERMUTATION (R1): within every 16-key block of the S^T tile, C-row
// positions hold keys sigma = [0-3, 8-11, 4-7, 12-15] (groups 1<->2 swapped).
// With this order, the quad-transpose of P needed between softmax and PV is
// EXACTLY swap(lane-bit5, reg-bit) = one v_permlane32_swap_b32 per dword
// pair -> sP eliminated, P lives entirely in registers.
// R3 POST-MORTEM: R1/R2 regressions were NOT a write-path problem — the
// __launch_bounds__(256,6) VGPR cap (~85) forced scratch spilling
// (VGPR_Count=40 vs ~100 live; +47MB fetch, +140MB write of spill traffic).
// Fix: (256,4) -> VGPR cap ~128, no spills, 4 blocks/CU (16 waves/CU).
// ---------------------------------------------------------------------------

// Weight prep: WqT[j][k] = Wq[k][j]; WpT[j][k'] with k' = h*32+dd (32-padded
// head-slab k-layout matching where attn leaves x in LDS), k = h*30+dd.
__global__ __launch_bounds__(256) void wt_prep_kernel(
    const float* __restrict__ Wq, const float* __restrict__ Wp,
    u16* __restrict__ WqT, u16* __restrict__ WpT) {
    int idx = blockIdx.x * 256 + threadIdx.x;        // < 2*192*192
    int sel = idx >= WPAD * WPAD;
    int rr  = sel ? idx - WPAD * WPAD : idx;
    int j = rr / WPAD, k = rr - j * WPAD;
    float v;
    if (!sel) {
        v = (j < DIM && k < DIM) ? Wq[k * DIM + j] : 0.f;
        WqT[j * WPAD + k] = f2bf(v);
    } else {
        int h = k >> 5, dd = k & 31;
        v = (j < DIM && dd < HD) ? Wp[(h * HD + dd) * DIM + j] : 0.f;
        WpT[j * WPAD + k] = f2bf(v);
    }
}

// ---------------------------------------------------------------------------
// Bias pre-gather in S^T C-fragment order WITH key permutation sigma: tile
// (h, g=q/16, t=n/16); lane (l15,quad) holds C-rows 16t+quad*4+r which carry
// keys 16t + pg*4 + r, pg = bit-reversed quad (0,2,1,3). col q=16g+l15.
__global__ __launch_bounds__(256) void gather_bias_kernel(
    const float* __restrict__ table, const int* __restrict__ rpi,
    u16* __restrict__ biasCT) {
    int i = blockIdx.x * 256 + threadIdx.x;          // < 7776*64 = 497664
    int lane = i & 63;
    int tile = i >> 6;
    int t = tile % 9;
    int rem = tile / 9;
    int g = rem % 144;
    int h = rem / 144;
    int qd = (lane >> 4) & 3;
    int pg = ((qd & 1) << 1) | (qd >> 1);            // sigma group: 0,2,1,3
    int q  = 16 * g + (lane & 15);
    int n0 = 16 * t + pg * 4;
    const int4 rr = *(const int4*)&rpi[q * NKEY + n0];
    unsigned lo = (unsigned)f2bf(table[rr.x * HEADS + h]) |
                  ((unsigned)f2bf(table[rr.y * HEADS + h]) << 16);
    unsigned hi = (unsigned)f2bf(table[rr.z * HEADS + h]) |
                  ((unsigned)f2bf(table[rr.w * HEADS + h]) << 16);
    ((uint2*)biasCT)[i] = make_uint2(lo, hi);
}

// ---------------------------------------------------------------------------
// K/V projection -> bf16 fragment-ready global layouts:
//   Kb [b][h][n'][40]  (row n' = sigma^-1(n); d pad 30..39 = 0 via memset)
//   VbT[b][h][d][144]  (natural key order; d rows 30,31 = 0 via memset)
__global__ __launch_bounds__(256) void kv_proj_kernel(
    const float* __restrict__ feat,
    const float* __restrict__ Wk, const float* __restrict__ bk,
    const float* __restrict__ Wv, const float* __restrict__ bv,
    u16* __restrict__ Kb, u16* __restrict__ VbT) {
    __shared__ float sF[16 * DIM];
    int b  = blockIdx.x / 9;
    int n0 = (blockIdx.x % 9) * 16;
    int tid = threadIdx.x;
    {
        const float4* src = (const float4*)(feat + (size_t)(b * NKEY + n0) * DIM);
        float4* dst = (float4*)sF;
        for (int i = tid; i < 16 * 45; i += 256) dst[i] = src[i];
    }
    __syncthreads();
    int j = tid;
    if (j < DIM) {
        float ak[16], av[16];
#pragma unroll
        for (int r = 0; r < 16; ++r) { ak[r] = 0.f; av[r] = 0.f; }
        const float4* sF4 = (const float4*)sF;
        for (int kc = 0; kc < 45; ++kc) {
            int kk = kc * 4;
            float wk0 = Wk[(kk + 0) * DIM + j], wk1 = Wk[(kk + 1) * DIM + j];
            float wk2 = Wk[(kk + 2) * DIM + j], wk3 = Wk[(kk + 3) * DIM + j];
            float wv0 = Wv[(kk + 0) * DIM + j], wv1 = Wv[(kk + 1) * DIM + j];
            float wv2 = Wv[(kk + 2) * DIM + j], wv3 = Wv[(kk + 3) * DIM + j];
#pragma unroll
            for (int r = 0; r < 16; ++r) {
                float4 g = sF4[r * 45 + kc];
                ak[r] = fmaf(g.x, wk0, ak[r]); ak[r] = fmaf(g.y, wk1, ak[r]);
                ak[r] = fmaf(g.z, wk2, ak[r]); ak[r] = fmaf(g.w, wk3, ak[r]);
                av[r] = fmaf(g.x, wv0, av[r]); av[r] = fmaf(g.y, wv1, av[r]);
                av[r] = fmaf(g.z, wv2, av[r]); av[r] = fmaf(g.w, wv3, av[r]);
            }
        }
        int h = j / HD, d = j - HD * h;
        u16* kp = Kb  + (size_t)(b * HEADS + h) * KB_STRIDE;
        u16* vp = VbT + (size_t)(b * HEADS + h) * VB_STRIDE;
        float bkj = bk[j], bvj = bv[j];
#pragma unroll
        for (int r = 0; r < 16; ++r) {
            // key n0+r lands at row position n0+sr (sigma involution)
            int sr = ((r >> 2) == 1) ? r + 4 : ((r >> 2) == 2) ? r - 4 : r;
            kp[(n0 + sr) * KROW + d] = f2bf(ak[r] + bkj);
            vp[d * VROW + n0 + r]    = f2bf(av[r] + bvj);
        }
    }
}

// ---------------------------------------------------------------------------
// Fused MFMA attention. One block = (batch, 64-query tile), 4 waves.
// LDS: sXQ only = 25600 B. Occupancy binder is now VGPRs: (256,4) -> cap
// ~128 VGPRs, no spills, 4 blocks/CU = 16 waves/CU.
// Head loop is BARRIER-FREE: K/V/bias fragments come straight from global
// (L2/L3-resident); P lives entirely in registers (permlane32_swap quad
// transpose, enabled by key-order sigma). XCD-swizzled blockIdx (blocks on
// one XCD share b -> K/V L2 locality); LDS-staged coalesced f32 epilogue.
__global__ __launch_bounds__(256, 4) void attn_kernel(
    const float* __restrict__ gs,
    const u16* __restrict__ WqT, const float* __restrict__ bq,
    const u16* __restrict__ WpT, const float* __restrict__ bp,
    const u16* __restrict__ Kb, const u16* __restrict__ VbT,
    const u16* __restrict__ biasCT, float* __restrict__ out) {

    __shared__ __align__(16) u16 sXQ[TQ * SXS]; // gs -> Q -> x -> f32 out tile

    const int tid  = threadIdx.x;
    const int w    = tid >> 6;        // wave 0..3
    const int lane = tid & 63;
    const int l15  = tid & 15;
    const int quad = (tid >> 4) & 3;
    // bijective XCD swizzle: 2304 blocks, 8 XCDs, 288/XCD contiguous chunk.
    // Concurrent blocks on an XCD then share b (K/V L2 locality).
    const int bid  = blockIdx.x;
    const int swz  = (bid & 7) * (BATCH * QT / 8) + (bid >> 3);
    const int b    = swz / QT;
    const int qt   = swz - b * QT;
    const int q0   = qt * TQ;
    const float SCALE = 0.18257418583505536f;   // 1/sqrt(30)

    // ---- stage gs tile -> sXQ (bf16, zero pad cols 180..195) ----
    {
        const float4* src = (const float4*)(gs + (size_t)(b * NGS + q0) * DIM);
        for (int i = tid; i < TQ * 45; i += 256) {
            int row = i / 45, c = i - row * 45;
            float4 g = src[row * 45 + c];
            unsigned lo = (unsigned)f2bf(g.x) | ((unsigned)f2bf(g.y) << 16);
            unsigned hi = (unsigned)f2bf(g.z) | ((unsigned)f2bf(g.w) << 16);
            *(uint2*)&sXQ[row * SXS + c * 4] = make_uint2(lo, hi);
        }
        for (int i = tid; i < TQ * 16; i += 256)
            sXQ[(i >> 4) * SXS + 180 + (i & 15)] = 0;
    }
    __syncthreads();

    // ---- Q-proj: q = (gs @ Wq + bq)*scale. Accumulate in regs, then
    //      overwrite the (dead) gs tile with Q in 32-padded head-slab cols.
    v4f qacc[12];
#pragma unroll
    for (int i = 0; i < 12; ++i) qacc[i] = (v4f){0.f, 0.f, 0.f, 0.f};
    for (int kt = 0; kt < 6; ++kt) {
        v8s A[4];
#pragma unroll
        for (int m = 0; m < 4; ++m)
            A[m] = *(const v8s*)&sXQ[(16 * m + l15) * SXS + kt * 32 + quad * 8];
#pragma unroll
        for (int jj = 0; jj < 3; ++jj) {
            v8s B = *(const v8s*)&WqT[(size_t)((3 * w + jj) * 16 + l15) * WPAD +
                                      kt * 32 + quad * 8];
#pragma unroll
            for (int m = 0; m < 4; ++m)
                qacc[jj * 4 + m] = __builtin_amdgcn_mfma_f32_16x16x32_bf16(
                    A[m], B, qacc[jj * 4 + m], 0, 0, 0);
        }
    }
    __syncthreads();   // all waves done READING gs before Q overwrites it
#pragma unroll
    for (int jj = 0; jj < 3; ++jj) {
        int j = (3 * w + jj) * 16 + l15;
        if (j < DIM) {
            int h = j / HD;
            int pos = j + 2 * h;          // 32-padded head-slab column
            float bqj = bq[j];
#pragma unroll
            for (int m = 0; m < 4; ++m)
#pragma unroll
                for (int r = 0; r < 4; ++r)
                    sXQ[(16 * m + quad * 4 + r) * SXS + pos] =
                        f2bf((qacc[jj * 4 + m][r] + bqj) * SCALE);
        }
    }
    // zero Q pad cols d=30,31 of every head slab
    for (int i = tid; i < TQ * 12; i += 256) {
        int row = i / 12, c = i - row * 12;
        sXQ[row * SXS + (c >> 1) * 32 + 30 + (c & 1)] = 0;
    }
    __syncthreads();

    // ---- per-head attention (no barriers inside) ----
    for (int h = 0; h < HEADS; ++h) {
        const u16* kp = Kb  + (size_t)(b * HEADS + h) * KB_STRIDE;
        const u16* vp = VbT + (size_t)(b * HEADS + h) * VB_STRIDE;

        // Q B-fragment: own q rows (16w+l15), this head's 32-col slab
        v8s qa = *(const v8s*)&sXQ[(16 * w + l15) * SXS + h * 32 + quad * 8];

        // S^T = K · Q^T + bias^T : A = K rows (permuted keys), B = Q.
        // C tile t: rowpos n'=16t+quad*4+r (key sigma(n')), col q=16w+l15.
        v4f la[9];
        const u16* bgt = biasCT +
            ((size_t)((h * 144 + (qt * 4 + w)) * 9) * 256) + lane * 4;
#pragma unroll
        for (int t = 0; t < 9; ++t) {
            uint2 bb = *(const uint2*)(bgt + t * 256);
            v4f c;
            c[0] = bf2f((u16)(bb.x & 0xffff));
            c[1] = bf2f((u16)(bb.x >> 16));
            c[2] = bf2f((u16)(bb.y & 0xffff));
            c[3] = bf2f((u16)(bb.y >> 16));
            v8s kb = *(const v8s*)&kp[(16 * t + l15) * KROW + quad * 8];
            la[t] = __builtin_amdgcn_mfma_f32_16x16x32_bf16(kb, qa, c, 0, 0, 0);
        }

        // softmax: all 36 values in this lane share q = 16w+l15; quads hold
        // disjoint keys -> reduce across quads with xor 16,32 only.
        float m = la[0][0];
#pragma unroll
        for (int t = 0; t < 9; ++t)
#pragma unroll
            for (int r = 0; r < 4; ++r) m = fmaxf(m, la[t][r]);
        m = fmaxf(m, __shfl_xor(m, 16));
        m = fmaxf(m, __shfl_xor(m, 32));
        float s = 0.f;
#pragma unroll
        for (int t = 0; t < 9; ++t)
#pragma unroll
            for (int r = 0; r < 4; ++r) {
                la[t][r] = __expf(la[t][r] - m);
                s += la[t][r];
            }
        s += __shfl_xor(s, 16);
        s += __shfl_xor(s, 32);
        float inv = 1.f / s;

        // pack P rows to bf16 dwords: sd0[t]=keys(rowpos 4q+0,1),
        // sd1[t]=keys(rowpos 4q+2,3) of tile t, scaled by inv.
        unsigned sd0[9], sd1[9];
#pragma unroll
        for (int t = 0; t < 9; ++t) {
            sd0[t] = (unsigned)f2bf(la[t][0] * inv) |
                     ((unsigned)f2bf(la[t][1] * inv) << 16);
            sd1[t] = (unsigned)f2bf(la[t][2] * inv) |
                     ((unsigned)f2bf(la[t][3] * inv) << 16);
        }

        // x^T = V^T · P^T : A = V^T rows (lane=d), B = P^T (lane=q col).
        // B-fragment (8 contiguous keys per lane) is produced IN-REGISTER:
        // thanks to sigma, dest(lane-b5, reg) = src(reg, lane-b5), which is
        // exactly v_permlane32_swap_b32 on dword pairs. kt=4 swaps against
        // zero regs -> keys 144..159 are zero.
        v4f x0 = (v4f){0.f, 0.f, 0.f, 0.f}, x1 = x0;
#pragma unroll
        for (int kt = 0; kt < 5; ++kt) {
            unsigned d0, d1, d2, d3;
            if (kt < 4) {
                d0 = sd0[2 * kt];     d1 = sd1[2 * kt];
                d2 = sd0[2 * kt + 1]; d3 = sd1[2 * kt + 1];
            } else {
                d0 = sd0[8]; d1 = sd1[8]; d2 = 0u; d3 = 0u;
            }
            asm("v_permlane32_swap_b32 %0, %1" : "+v"(d0), "+v"(d2));
            asm("v_permlane32_swap_b32 %0, %1" : "+v"(d1), "+v"(d3));
            union { unsigned u[4]; v8s v; } pu;
            pu.u[0] = d0; pu.u[1] = d1; pu.u[2] = d2; pu.u[3] = d3;
            int co = kt * 32 + quad * 8;
            co = (co < NKEY) ? co : 0;       // pa is zero there (kt=4,q>=2)
            v8s a0 = *(const v8s*)&vp[l15 * VROW + co];
            v8s a1 = *(const v8s*)&vp[(16 + l15) * VROW + co];
            x0 = __builtin_amdgcn_mfma_f32_16x16x32_bf16(a0, pu.v, x0, 0, 0, 0);
            x1 = __builtin_amdgcn_mfma_f32_16x16x32_bf16(a1, pu.v, x1, 0, 0, 0);
        }
        // x^T C tile: row d=quad*4+r (tile0) / 16+quad*4+r (tile1), col q=l15.
        // Write x[q][h*32+d] into the dead Q slab h; d=30,31 are zero because
        // VbT rows 30,31 are zero. 4 consecutive cols -> ds_write_b64.
        *(uint2*)&sXQ[(16 * w + l15) * SXS + h * 32 + quad * 4]      = pack4(x0);
        *(uint2*)&sXQ[(16 * w + l15) * SXS + h * 32 + 16 + quad * 4] = pack4(x1);
    }
    __syncthreads();   // x rows are read cross-wave by out-proj

    // ---- out-proj: out = x @ Wp + bp (WpT is in matching 32-padded k-layout)
    {
        v4f acc[12];
#pragma unroll
        for (int i = 0; i < 12; ++i) acc[i] = (v4f){0.f, 0.f, 0.f, 0.f};
        for (int kt = 0; kt < 6; ++kt) {
            v8s A[4];
#pragma unroll
            for (int m = 0; m < 4; ++m)
                A[m] = *(const v8s*)&sXQ[(16 * m + l15) * SXS + kt * 32 + quad * 8];
#pragma unroll
            for (int jj = 0; jj < 3; ++jj) {
                v8s B = *(const v8s*)&WpT[(size_t)((3 * w + jj) * 16 + l15) * WPAD +
                                          kt * 32 + quad * 8];
#pragma unroll
                for (int m = 0; m < 4; ++m)
                    acc[jj * 4 + m] = __builtin_amdgcn_mfma_f32_16x16x32_bf16(
                        A[m], B, acc[jj * 4 + m], 0, 0, 0);
            }
        }
        __syncthreads();   // all sXQ reads done; reuse it as f32 out staging

        // epilogue: stage 32 rows (23040 B fits sXQ) then store the block's
        // CONTIGUOUS out tile with full-line float4 stores.
        float* sOutF = (float*)sXQ;
#pragma unroll
        for (int half = 0; half < 2; ++half) {
#pragma unroll
            for (int jj = 0; jj < 3; ++jj) {
                int j = (3 * w + jj) * 16 + l15;
                if (j < DIM) {
                    float bpj = bp[j];
#pragma unroll
                    for (int m = 0; m < 2; ++m) {        // local row group
                        int mm = half * 2 + m;           // acc row group
#pragma unroll
                        for (int r = 0; r < 4; ++r)
                            sOutF[(16 * m + quad * 4 + r) * DIM + j] =
                                acc[jj * 4 + mm][r] + bpj;
                    }
                }
            }
            __syncthreads();
            const float4* s4 = (const float4*)sOutF;
            float4* dst = (float4*)(out + (size_t)(b * NGS + q0 + 32 * half) * DIM);
            for (int i = tid; i < 32 * DIM / 4; i += 256) dst[i] = s4[i];
            if (half == 0) __syncthreads();  // staging reused by half 1
        }
    }
}

// ---------------------------------------------------------------------------
extern "C" void kernel_launch(void* const* d_in, const int* in_sizes, int n_in,
                              void* d_out, int out_size, void* d_ws, size_t ws_size,
                              hipStream_t stream) {
    const float* gs    = (const float*)d_in[0];
    const float* feat  = (const float*)d_in[1];
    const float* Wq    = (const float*)d_in[2];
    const float* bq    = (const float*)d_in[3];
    const float* Wk    = (const float*)d_in[4];
    const float* bk    = (const float*)d_in[5];
    const float* Wv    = (const float*)d_in[6];
    const float* bv    = (const float*)d_in[7];
    const float* Wp    = (const float*)d_in[8];
    const float* bp    = (const float*)d_in[9];
    const float* table = (const float*)d_in[10];
    const int*   rpi   = (const int*)d_in[11];
    float* out = (float*)d_out;

    // ws layout (u16 units): WqT | WpT | Kb | VbT | biasCT  (~12.1 MB)
    u16* WqT    = (u16*)d_ws;
    u16* WpT    = WqT + WPAD * WPAD;
    u16* Kb     = WpT + WPAD * WPAD;
    u16* VbT    = Kb  + (size_t)BATCH * HEADS * KB_STRIDE;
    u16* biasCT = VbT + (size_t)BATCH * HEADS * VB_STRIDE;

    // zero K pads (d=30..39) and V pad rows (d=30,31): MFMA reads them
    size_t zero_bytes = (size_t)BATCH * HEADS * (KB_STRIDE + VB_STRIDE) * sizeof(u16);
    hipMemsetAsync(Kb, 0, zero_bytes, stream);

    wt_prep_kernel<<<dim3(2 * WPAD * WPAD / 256), dim3(256), 0, stream>>>(Wq, Wp, WqT, WpT);
    gather_bias_kernel<<<dim3(HEADS * 144 * 9 * 64 / 256), dim3(256), 0, stream>>>(
        table, rpi, biasCT);
    kv_proj_kernel<<<dim3(BATCH * 9), dim3(256), 0, stream>>>(feat, Wk, bk, Wv, bv, Kb, VbT);
    attn_kernel<<<dim3(BATCH * QT), dim3(256), 0, stream>>>(
        gs, WqT, bq, WpT, bp, Kb, VbT, biasCT, out);
}

// Round 4
// 380.974 us; speedup vs baseline: 1.1448x; 1.0679x over previous
//
#include <hip/hip_runtime.h>

// Problem constants
#define DIM   180
#define HEADS 6
#define HD    30
#define NKEY  144
#define NGS   2304
#define BATCH 64
#define TQ    64
#define QT    36                // q-tiles (2304/64)
#define WPAD  192               // padded model dim (6 k-tiles of 32)
#define SXS   200               // sXQ row stride u16 (400 B = 25*16, rows 16B-aligned)
#define SPS   152               // sP  row stride u16 (304 B = 19*16)
#define KROW  40                // Kb row stride u16 (80 B, 16B-aligned)
#define VROW  144               // VbT row stride u16 (288 B, 16B-aligned)
#define KB_STRIDE (NKEY * KROW) // 5760 u16 per (b,h)
#define VB_STRIDE (32 * VROW)   // 4608 u16 per (b,h)

typedef unsigned short u16;
typedef short v8s __attribute__((ext_vector_type(8)));   // 8 x bf16 MFMA operand
typedef float v4f __attribute__((ext_vector_type(4)));   // 4 x f32 MFMA acc

__device__ __forceinline__ float bf2f(u16 u) {
    union { unsigned int i; float f; } w; w.i = ((unsigned int)u) << 16; return w.f;
}
__device__ __forceinline__ u16 f2bf(float f) {
    union { float f; unsigned int i; } w; w.f = f;
    unsigned int r = w.i + 0x7fffu + ((w.i >> 16) & 1u);
    return (u16)(r >> 16);
}
__device__ __forceinline__ uint2 pack4(const v4f& x) {
    uint2 r;
    r.x = (unsigned)f2bf(x[0]) | ((unsigned)f2bf(x[1]) << 16);
    r.y = (unsigned)f2bf(x[2]) | ((unsigned)f2bf(x[3]) << 16);
    return r;
}

// ---------------------------------------------------------------------------
// R4: revert to the R0 structure (sP LDS round-trip, 3 blocks/CU, direct
// epilogue) — the in-register-P variants (R1-R3) were all slower even when
// clean. NEW: (a) 2D locality swizzle — each XCD owns 8 batches for all qt,
// so its concurrent blocks' K/V (8x124KB) + bias (12x110KB) working set
// fits the 4MB XCD L2; previously random (b,qt) placement put ~8MB K/V +
// 4MB bias per XCD -> every operand load was an L3 hit (~600-900cy) and the
// per-head load phases exposed that latency (90%+ wave stall, MfmaUtil 9%).
// (b) log2e folded into Q-scale and bias so softmax uses raw v_exp_f32.
// ---------------------------------------------------------------------------

// Weight prep: WqT[j][k] = Wq[k][j]; WpT[j][k'] with k' = h*32+dd (32-padded
// head-slab k-layout matching where attn leaves x in LDS), k = h*30+dd.
__global__ __launch_bounds__(256) void wt_prep_kernel(
    const float* __restrict__ Wq, const float* __restrict__ Wp,
    u16* __restrict__ WqT, u16* __restrict__ WpT) {
    int idx = blockIdx.x * 256 + threadIdx.x;        // < 2*192*192
    int sel = idx >= WPAD * WPAD;
    int rr  = sel ? idx - WPAD * WPAD : idx;
    int j = rr / WPAD, k = rr - j * WPAD;
    float v;
    if (!sel) {
        v = (j < DIM && k < DIM) ? Wq[k * DIM + j] : 0.f;
        WqT[j * WPAD + k] = f2bf(v);
    } else {
        int h = k >> 5, dd = k & 31;
        v = (j < DIM && dd < HD) ? Wp[(h * HD + dd) * DIM + j] : 0.f;
        WpT[j * WPAD + k] = f2bf(v);
    }
}

// ---------------------------------------------------------------------------
// Bias pre-gather in S^T C-fragment order: tile (h, g=q/16, t=n/16); lane
// (l15,quad) holds rows n=16t+quad*4+r, col q=16g+l15 (C: col=lane&15,
// row=quad*4+r). One uint2 (4 bf16) per lane -> coalesced dwordx2 in attn.
// Values pre-scaled by log2e (softmax runs in the exp2 domain).
__global__ __launch_bounds__(256) void gather_bias_kernel(
    const float* __restrict__ table, const int* __restrict__ rpi,
    u16* __restrict__ biasCT) {
    const float LOG2E = 1.4426950408889634f;
    int i = blockIdx.x * 256 + threadIdx.x;          // < 7776*64 = 497664
    int lane = i & 63;
    int tile = i >> 6;
    int t = tile % 9;
    int rem = tile / 9;
    int g = rem % 144;
    int h = rem / 144;
    int q  = 16 * g + (lane & 15);
    int n0 = 16 * t + (lane >> 4) * 4;
    const int4 rr = *(const int4*)&rpi[q * NKEY + n0];
    unsigned lo = (unsigned)f2bf(table[rr.x * HEADS + h] * LOG2E) |
                  ((unsigned)f2bf(table[rr.y * HEADS + h] * LOG2E) << 16);
    unsigned hi = (unsigned)f2bf(table[rr.z * HEADS + h] * LOG2E) |
                  ((unsigned)f2bf(table[rr.w * HEADS + h] * LOG2E) << 16);
    ((uint2*)biasCT)[i] = make_uint2(lo, hi);
}

// ---------------------------------------------------------------------------
// K/V projection -> bf16 fragment-ready global layouts:
//   Kb [b][h][n][40]   (d pad 30..39 = 0 via memset)  -- S^T A-operand rows
//   VbT[b][h][d][144]  (d rows 30,31 = 0 via memset)  -- x^T A-operand rows
__global__ __launch_bounds__(256) void kv_proj_kernel(
    const float* __restrict__ feat,
    const float* __restrict__ Wk, const float* __restrict__ bk,
    const float* __restrict__ Wv, const float* __restrict__ bv,
    u16* __restrict__ Kb, u16* __restrict__ VbT) {
    __shared__ float sF[16 * DIM];
    int b  = blockIdx.x / 9;
    int n0 = (blockIdx.x % 9) * 16;
    int tid = threadIdx.x;
    {
        const float4* src = (const float4*)(feat + (size_t)(b * NKEY + n0) * DIM);
        float4* dst = (float4*)sF;
        for (int i = tid; i < 16 * 45; i += 256) dst[i] = src[i];
    }
    __syncthreads();
    int j = tid;
    if (j < DIM) {
        float ak[16], av[16];
#pragma unroll
        for (int r = 0; r < 16; ++r) { ak[r] = 0.f; av[r] = 0.f; }
        const float4* sF4 = (const float4*)sF;
        for (int kc = 0; kc < 45; ++kc) {
            int kk = kc * 4;
            float wk0 = Wk[(kk + 0) * DIM + j], wk1 = Wk[(kk + 1) * DIM + j];
            float wk2 = Wk[(kk + 2) * DIM + j], wk3 = Wk[(kk + 3) * DIM + j];
            float wv0 = Wv[(kk + 0) * DIM + j], wv1 = Wv[(kk + 1) * DIM + j];
            float wv2 = Wv[(kk + 2) * DIM + j], wv3 = Wv[(kk + 3) * DIM + j];
#pragma unroll
            for (int r = 0; r < 16; ++r) {
                float4 g = sF4[r * 45 + kc];
                ak[r] = fmaf(g.x, wk0, ak[r]); ak[r] = fmaf(g.y, wk1, ak[r]);
                ak[r] = fmaf(g.z, wk2, ak[r]); ak[r] = fmaf(g.w, wk3, ak[r]);
                av[r] = fmaf(g.x, wv0, av[r]); av[r] = fmaf(g.y, wv1, av[r]);
                av[r] = fmaf(g.z, wv2, av[r]); av[r] = fmaf(g.w, wv3, av[r]);
            }
        }
        int h = j / HD, d = j - HD * h;
        u16* kp = Kb  + (size_t)(b * HEADS + h) * KB_STRIDE;
        u16* vp = VbT + (size_t)(b * HEADS + h) * VB_STRIDE;
        float bkj = bk[j], bvj = bv[j];
#pragma unroll
        for (int r = 0; r < 16; ++r) {
            kp[(n0 + r) * KROW + d] = f2bf(ak[r] + bkj);
            vp[d * VROW + n0 + r]   = f2bf(av[r] + bvj);
        }
    }
}

// ---------------------------------------------------------------------------
// Fused MFMA attention. One block = (batch, 64-query tile), 4 waves.
// LDS: sXQ 25600 + sP 19456 = 45056 B -> 3 blocks/CU (12 waves/CU).
// Head loop is BARRIER-FREE: K/V/bias fragments come straight from global
// (L2-resident thanks to the R4 swizzle), P and x touch only wave-private
// rows. S^T/x^T formulation puts each softmax row in one lane (2 shuffles)
// and makes P/x writes b64.
__global__ __launch_bounds__(256, 3) void attn_kernel(
    const float* __restrict__ gs,
    const u16* __restrict__ WqT, const float* __restrict__ bq,
    const u16* __restrict__ WpT, const float* __restrict__ bp,
    const u16* __restrict__ Kb, const u16* __restrict__ VbT,
    const u16* __restrict__ biasCT, float* __restrict__ out) {

    __shared__ u16 sXQ[TQ * SXS];  // gs tile -> Q (head-slab layout) -> x
    __shared__ u16 sP[TQ * SPS];   // P rows [q][n], wave-private 16-row slabs

    const int tid  = threadIdx.x;
    const int w    = tid >> 6;        // wave 0..3
    const int lane = tid & 63;
    const int l15  = tid & 15;
    const int quad = (tid >> 4) & 3;
    // R4 2D locality swizzle: xcd = bid&7 (HW round-robin), each XCD owns
    // b in [8*xcd, 8*xcd+8) for ALL qt; within an XCD consecutive blocks
    // sweep b fastest -> concurrent window = 8 b x ~12 qt -> K/V+bias
    // working set ~2.3MB fits the 4MB XCD L2 (was ~12MB -> all L3 hits).
    const int bid  = blockIdx.x;
    const int i8   = bid >> 3;           // 0..287 within XCD
    const int qt   = i8 >> 3;            // 0..35
    const int b    = (bid & 7) * 8 + (i8 & 7);
    const int q0   = qt * TQ;
    // 1/sqrt(30) * log2e : softmax runs in the exp2 domain
    const float SCALE = 0.18257418583505536f * 1.4426950408889634f;

    // ---- stage gs tile -> sXQ (bf16, zero pad cols 180..195) ----
    {
        const float4* src = (const float4*)(gs + (size_t)(b * NGS + q0) * DIM);
        for (int i = tid; i < TQ * 45; i += 256) {
            int row = i / 45, c = i - row * 45;
            float4 g = src[row * 45 + c];
            unsigned lo = (unsigned)f2bf(g.x) | ((unsigned)f2bf(g.y) << 16);
            unsigned hi = (unsigned)f2bf(g.z) | ((unsigned)f2bf(g.w) << 16);
            *(uint2*)&sXQ[row * SXS + c * 4] = make_uint2(lo, hi);
        }
        for (int i = tid; i < TQ * 16; i += 256)
            sXQ[(i >> 4) * SXS + 180 + (i & 15)] = 0;
    }
    __syncthreads();

    // ---- Q-proj: q = (gs @ Wq + bq)*scale. Accumulate in regs, then
    //      overwrite the (dead) gs tile with Q in 32-padded head-slab cols.
    v4f qacc[12];
#pragma unroll
    for (int i = 0; i < 12; ++i) qacc[i] = (v4f){0.f, 0.f, 0.f, 0.f};
    for (int kt = 0; kt < 6; ++kt) {
        v8s A[4];
#pragma unroll
        for (int m = 0; m < 4; ++m)
            A[m] = *(const v8s*)&sXQ[(16 * m + l15) * SXS + kt * 32 + quad * 8];
#pragma unroll
        for (int jj = 0; jj < 3; ++jj) {
            v8s B = *(const v8s*)&WqT[(size_t)((3 * w + jj) * 16 + l15) * WPAD +
                                      kt * 32 + quad * 8];
#pragma unroll
            for (int m = 0; m < 4; ++m)
                qacc[jj * 4 + m] = __builtin_amdgcn_mfma_f32_16x16x32_bf16(
                    A[m], B, qacc[jj * 4 + m], 0, 0, 0);
        }
    }
    __syncthreads();   // all waves done READING gs before Q overwrites it
#pragma unroll
    for (int jj = 0; jj < 3; ++jj) {
        int j = (3 * w + jj) * 16 + l15;
        if (j < DIM) {
            int h = j / HD;
            int pos = j + 2 * h;          // 32-padded head-slab column
            float bqj = bq[j];
#pragma unroll
            for (int m = 0; m < 4; ++m)
#pragma unroll
                for (int r = 0; r < 4; ++r)
                    sXQ[(16 * m + quad * 4 + r) * SXS + pos] =
                        f2bf((qacc[jj * 4 + m][r] + bqj) * SCALE);
        }
    }
    // zero Q pad cols d=30,31 of every head slab
    for (int i = tid; i < TQ * 12; i += 256) {
        int row = i / 12, c = i - row * 12;
        sXQ[row * SXS + (c >> 1) * 32 + 30 + (c & 1)] = 0;
    }
    __syncthreads();

    // ---- per-head attention (no barriers inside) ----
    for (int h = 0; h < HEADS; ++h) {
        const u16* kp = Kb  + (size_t)(b * HEADS + h) * KB_STRIDE;
        const u16* vp = VbT + (size_t)(b * HEADS + h) * VB_STRIDE;

        // Q B-fragment: own q rows (16w+l15), this head's 32-col slab
        v8s qa = *(const v8s*)&sXQ[(16 * w + l15) * SXS + h * 32 + quad * 8];

        // S^T = K · Q^T + bias^T : A = K rows (lane=n), B = Q (lane=q col).
        // C tile t: row n=16t+quad*4+r, col q=16w+l15.
        v4f la[9];
        const u16* bgt = biasCT +
            ((size_t)((h * 144 + (qt * 4 + w)) * 9) * 256) + lane * 4;
#pragma unroll
        for (int t = 0; t < 9; ++t) {
            uint2 bb = *(const uint2*)(bgt + t * 256);
            v4f c;
            c[0] = bf2f((u16)(bb.x & 0xffff));
            c[1] = bf2f((u16)(bb.x >> 16));
            c[2] = bf2f((u16)(bb.y & 0xffff));
            c[3] = bf2f((u16)(bb.y >> 16));
            v8s kb = *(const v8s*)&kp[(16 * t + l15) * KROW + quad * 8];
            la[t] = __builtin_amdgcn_mfma_f32_16x16x32_bf16(kb, qa, c, 0, 0, 0);
        }

        // softmax (exp2 domain): all 36 values in this lane share q=16w+l15;
        // quads hold disjoint n -> reduce across quads with xor 16,32 only.
        float m = la[0][0];
#pragma unroll
        for (int t = 0; t < 9; ++t)
#pragma unroll
            for (int r = 0; r < 4; ++r) m = fmaxf(m, la[t][r]);
        m = fmaxf(m, __shfl_xor(m, 16));
        m = fmaxf(m, __shfl_xor(m, 32));
        float s = 0.f;
#pragma unroll
        for (int t = 0; t < 9; ++t)
#pragma unroll
            for (int r = 0; r < 4; ++r) {
                la[t][r] = __builtin_amdgcn_exp2f(la[t][r] - m);
                s += la[t][r];
            }
        s += __shfl_xor(s, 16);
        s += __shfl_xor(s, 32);
        float inv = 1.f / s;

        // P -> own 16-row slab of sP, 4 consecutive n per lane = ds_write_b64
#pragma unroll
        for (int t = 0; t < 9; ++t) {
            v4f p;
#pragma unroll
            for (int r = 0; r < 4; ++r) p[r] = la[t][r] * inv;
            *(uint2*)&sP[(16 * w + l15) * SPS + 16 * t + quad * 4] = pack4(p);
        }

        // x^T = V^T · P^T : A = V^T rows (lane=d), B = P rows (lane=q col).
        // k covers n=0..159; the n=144..159 half (kt==4, quad>=2) is skipped
        // via zero regs (sP cols >=144 unwritten; VbT rows end at n=144).
        v4f x0 = (v4f){0.f, 0.f, 0.f, 0.f}, x1 = x0;
        for (int kt = 0; kt < 5; ++kt) {
            v8s pa = (v8s){0,0,0,0,0,0,0,0}, a0 = pa, a1 = pa;
            if (!(kt == 4 && quad >= 2)) {
                pa = *(const v8s*)&sP[(16 * w + l15) * SPS + kt * 32 + quad * 8];
                a0 = *(const v8s*)&vp[l15 * VROW + kt * 32 + quad * 8];
                a1 = *(const v8s*)&vp[(16 + l15) * VROW + kt * 32 + quad * 8];
            }
            x0 = __builtin_amdgcn_mfma_f32_16x16x32_bf16(a0, pa, x0, 0, 0, 0);
            x1 = __builtin_amdgcn_mfma_f32_16x16x32_bf16(a1, pa, x1, 0, 0, 0);
        }
        // x^T C tile: row d=quad*4+r (tile0) / 16+quad*4+r (tile1), col q=l15.
        // Write x[q][h*32+d] into the dead Q slab h; d=30,31 are zero because
        // VbT rows 30,31 are zero. 4 consecutive cols -> ds_write_b64.
        *(uint2*)&sXQ[(16 * w + l15) * SXS + h * 32 + quad * 4]      = pack4(x0);
        *(uint2*)&sXQ[(16 * w + l15) * SXS + h * 32 + 16 + quad * 4] = pack4(x1);
    }
    __syncthreads();   // x rows are read cross-wave by out-proj

    // ---- out-proj: out = x @ Wp + bp (WpT is in matching 32-padded k-layout)
    {
        v4f acc[12];
#pragma unroll
        for (int i = 0; i < 12; ++i) acc[i] = (v4f){0.f, 0.f, 0.f, 0.f};
        for (int kt = 0; kt < 6; ++kt) {
            v8s A[4];
#pragma unroll
            for (int m = 0; m < 4; ++m)
                A[m] = *(const v8s*)&sXQ[(16 * m + l15) * SXS + kt * 32 + quad * 8];
#pragma unroll
            for (int jj = 0; jj < 3; ++jj) {
                v8s B = *(const v8s*)&WpT[(size_t)((3 * w + jj) * 16 + l15) * WPAD +
                                          kt * 32 + quad * 8];
#pragma unroll
                for (int m = 0; m < 4; ++m)
                    acc[jj * 4 + m] = __builtin_amdgcn_mfma_f32_16x16x32_bf16(
                        A[m], B, acc[jj * 4 + m], 0, 0, 0);
            }
        }
#pragma unroll
        for (int jj = 0; jj < 3; ++jj) {
            int j = (3 * w + jj) * 16 + l15;
            if (j < DIM) {
                float bpj = bp[j];
#pragma unroll
                for (int m = 0; m < 4; ++m)
#pragma unroll
                    for (int r = 0; r < 4; ++r)
                        out[(size_t)(b * NGS + q0 + 16 * m + quad * 4 + r) * DIM + j] =
                            acc[jj * 4 + m][r] + bpj;
            }
        }
    }
}

// ---------------------------------------------------------------------------
extern "C" void kernel_launch(void* const* d_in, const int* in_sizes, int n_in,
                              void* d_out, int out_size, void* d_ws, size_t ws_size,
                              hipStream_t stream) {
    const float* gs    = (const float*)d_in[0];
    const float* feat  = (const float*)d_in[1];
    const float* Wq    = (const float*)d_in[2];
    const float* bq    = (const float*)d_in[3];
    const float* Wk    = (const float*)d_in[4];
    const float* bk    = (const float*)d_in[5];
    const float* Wv    = (const float*)d_in[6];
    const float* bv    = (const float*)d_in[7];
    const float* Wp    = (const float*)d_in[8];
    const float* bp    = (const float*)d_in[9];
    const float* table = (const float*)d_in[10];
    const int*   rpi   = (const int*)d_in[11];
    float* out = (float*)d_out;

    // ws layout (u16 units): WqT | WpT | Kb | VbT | biasCT  (~12.1 MB)
    u16* WqT    = (u16*)d_ws;
    u16* WpT    = WqT + WPAD * WPAD;
    u16* Kb     = WpT + WPAD * WPAD;
    u16* VbT    = Kb  + (size_t)BATCH * HEADS * KB_STRIDE;
    u16* biasCT = VbT + (size_t)BATCH * HEADS * VB_STRIDE;

    // zero K pads (d=30..39) and V pad rows (d=30,31): MFMA reads them
    size_t zero_bytes = (size_t)BATCH * HEADS * (KB_STRIDE + VB_STRIDE) * sizeof(u16);
    hipMemsetAsync(Kb, 0, zero_bytes, stream);

    wt_prep_kernel<<<dim3(2 * WPAD * WPAD / 256), dim3(256), 0, stream>>>(Wq, Wp, WqT, WpT);
    gather_bias_kernel<<<dim3(HEADS * 144 * 9 * 64 / 256), dim3(256), 0, stream>>>(
        table, rpi, biasCT);
    kv_proj_kernel<<<dim3(BATCH * 9), dim3(256), 0, stream>>>(feat, Wk, bk, Wv, bv, Kb, VbT);
    attn_kernel<<<dim3(BATCH * QT), dim3(256), 0, stream>>>(
        gs, WqT, bq, WpT, bp, Kb, VbT, biasCT, out);
}

// Round 5
// 376.789 us; speedup vs baseline: 1.1576x; 1.0111x over previous
//
#include <hip/hip_runtime.h>

// Problem constants
#define DIM   180
#define HEADS 6
#define HD    30
#define NKEY  144
#define NGS   2304
#define BATCH 64
#define TQ    64
#define QT    36                // q-tiles (2304/64)
#define WPAD  192               // padded model dim (6 k-tiles of 32)
#define SXS   200               // sXQ row stride u16 (400 B = 25*16, rows 16B-aligned)
#define SPS   152               // sP  row stride u16 (304 B = 19*16)
#define KROW  40                // Kb row stride u16 (80 B, 16B-aligned)
#define VROW  144               // VbT row stride u16 (288 B, 16B-aligned)
#define KB_STRIDE (NKEY * KROW) // 5760 u16 per (b,h)
#define VB_STRIDE (32 * VROW)   // 4608 u16 per (b,h)

typedef unsigned short u16;
typedef short v8s __attribute__((ext_vector_type(8)));   // 8 x bf16 MFMA operand
typedef float v4f __attribute__((ext_vector_type(4)));   // 4 x f32 MFMA acc

__device__ __forceinline__ float bf2f(u16 u) {
    union { unsigned int i; float f; } w; w.i = ((unsigned int)u) << 16; return w.f;
}
__device__ __forceinline__ u16 f2bf(float f) {
    union { float f; unsigned int i; } w; w.f = f;
    unsigned int r = w.i + 0x7fffu + ((w.i >> 16) & 1u);
    return (u16)(r >> 16);
}
// R5: single-instruction RNE f32->bf16 pair (our integer f2bf blocked the
// compiler from emitting v_cvt_pk_bf16_f32; 1 op replaces ~8).
__device__ __forceinline__ unsigned cvt_pk_bf16(float lo, float hi) {
    unsigned r;
    asm("v_cvt_pk_bf16_f32 %0, %1, %2" : "=v"(r) : "v"(lo), "v"(hi));
    return r;
}
__device__ __forceinline__ uint2 pack4(const v4f& x) {
    return make_uint2(cvt_pk_bf16(x[0], x[1]), cvt_pk_bf16(x[2], x[3]));
}

// ---------------------------------------------------------------------------
// R5: batched per-head loads. R4 showed locality is fine (FETCH 100->81 MB)
// but dur unchanged: VGPR_Count=68 proved the compiler never batched the
// per-head loads (bias was loaded inside the consuming MFMA iteration, V
// after softmax) -> ~5 exposed latency windows per head. Now: all 18 QK-side
// loads issue at head top into register arrays; all 10 V loads issue before
// softmax so their latency hides under it. P kept unnormalized in sP; inv
// applied to the 8 x outputs (saves 28 muls on the critical path).
// ---------------------------------------------------------------------------

// Weight prep: WqT[j][k] = Wq[k][j]; WpT[j][k'] with k' = h*32+dd (32-padded
// head-slab k-layout matching where attn leaves x in LDS), k = h*30+dd.
__global__ __launch_bounds__(256) void wt_prep_kernel(
    const float* __restrict__ Wq, const float* __restrict__ Wp,
    u16* __restrict__ WqT, u16* __restrict__ WpT) {
    int idx = blockIdx.x * 256 + threadIdx.x;        // < 2*192*192
    int sel = idx >= WPAD * WPAD;
    int rr  = sel ? idx - WPAD * WPAD : idx;
    int j = rr / WPAD, k = rr - j * WPAD;
    float v;
    if (!sel) {
        v = (j < DIM && k < DIM) ? Wq[k * DIM + j] : 0.f;
        WqT[j * WPAD + k] = f2bf(v);
    } else {
        int h = k >> 5, dd = k & 31;
        v = (j < DIM && dd < HD) ? Wp[(h * HD + dd) * DIM + j] : 0.f;
        WpT[j * WPAD + k] = f2bf(v);
    }
}

// ---------------------------------------------------------------------------
// Bias pre-gather in S^T C-fragment order: tile (h, g=q/16, t=n/16); lane
// (l15,quad) holds rows n=16t+quad*4+r, col q=16g+l15 (C: col=lane&15,
// row=quad*4+r). One uint2 (4 bf16) per lane -> coalesced dwordx2 in attn.
// Values pre-scaled by log2e (softmax runs in the exp2 domain).
__global__ __launch_bounds__(256) void gather_bias_kernel(
    const float* __restrict__ table, const int* __restrict__ rpi,
    u16* __restrict__ biasCT) {
    const float LOG2E = 1.4426950408889634f;
    int i = blockIdx.x * 256 + threadIdx.x;          // < 7776*64 = 497664
    int lane = i & 63;
    int tile = i >> 6;
    int t = tile % 9;
    int rem = tile / 9;
    int g = rem % 144;
    int h = rem / 144;
    int q  = 16 * g + (lane & 15);
    int n0 = 16 * t + (lane >> 4) * 4;
    const int4 rr = *(const int4*)&rpi[q * NKEY + n0];
    unsigned lo = (unsigned)f2bf(table[rr.x * HEADS + h] * LOG2E) |
                  ((unsigned)f2bf(table[rr.y * HEADS + h] * LOG2E) << 16);
    unsigned hi = (unsigned)f2bf(table[rr.z * HEADS + h] * LOG2E) |
                  ((unsigned)f2bf(table[rr.w * HEADS + h] * LOG2E) << 16);
    ((uint2*)biasCT)[i] = make_uint2(lo, hi);
}

// ---------------------------------------------------------------------------
// K/V projection -> bf16 fragment-ready global layouts:
//   Kb [b][h][n][40]   (d pad 30..39 = 0 via memset)  -- S^T A-operand rows
//   VbT[b][h][d][144]  (d rows 30,31 = 0 via memset)  -- x^T A-operand rows
__global__ __launch_bounds__(256) void kv_proj_kernel(
    const float* __restrict__ feat,
    const float* __restrict__ Wk, const float* __restrict__ bk,
    const float* __restrict__ Wv, const float* __restrict__ bv,
    u16* __restrict__ Kb, u16* __restrict__ VbT) {
    __shared__ float sF[16 * DIM];
    int b  = blockIdx.x / 9;
    int n0 = (blockIdx.x % 9) * 16;
    int tid = threadIdx.x;
    {
        const float4* src = (const float4*)(feat + (size_t)(b * NKEY + n0) * DIM);
        float4* dst = (float4*)sF;
        for (int i = tid; i < 16 * 45; i += 256) dst[i] = src[i];
    }
    __syncthreads();
    int j = tid;
    if (j < DIM) {
        float ak[16], av[16];
#pragma unroll
        for (int r = 0; r < 16; ++r) { ak[r] = 0.f; av[r] = 0.f; }
        const float4* sF4 = (const float4*)sF;
        for (int kc = 0; kc < 45; ++kc) {
            int kk = kc * 4;
            float wk0 = Wk[(kk + 0) * DIM + j], wk1 = Wk[(kk + 1) * DIM + j];
            float wk2 = Wk[(kk + 2) * DIM + j], wk3 = Wk[(kk + 3) * DIM + j];
            float wv0 = Wv[(kk + 0) * DIM + j], wv1 = Wv[(kk + 1) * DIM + j];
            float wv2 = Wv[(kk + 2) * DIM + j], wv3 = Wv[(kk + 3) * DIM + j];
#pragma unroll
            for (int r = 0; r < 16; ++r) {
                float4 g = sF4[r * 45 + kc];
                ak[r] = fmaf(g.x, wk0, ak[r]); ak[r] = fmaf(g.y, wk1, ak[r]);
                ak[r] = fmaf(g.z, wk2, ak[r]); ak[r] = fmaf(g.w, wk3, ak[r]);
                av[r] = fmaf(g.x, wv0, av[r]); av[r] = fmaf(g.y, wv1, av[r]);
                av[r] = fmaf(g.z, wv2, av[r]); av[r] = fmaf(g.w, wv3, av[r]);
            }
        }
        int h = j / HD, d = j - HD * h;
        u16* kp = Kb  + (size_t)(b * HEADS + h) * KB_STRIDE;
        u16* vp = VbT + (size_t)(b * HEADS + h) * VB_STRIDE;
        float bkj = bk[j], bvj = bv[j];
#pragma unroll
        for (int r = 0; r < 16; ++r) {
            kp[(n0 + r) * KROW + d] = f2bf(ak[r] + bkj);
            vp[d * VROW + n0 + r]   = f2bf(av[r] + bvj);
        }
    }
}

// ---------------------------------------------------------------------------
// Fused MFMA attention. One block = (batch, 64-query tile), 4 waves.
// LDS: sXQ 25600 + sP 19456 = 45056 B -> 3 blocks/CU (12 waves/CU).
// Head loop is BARRIER-FREE; K/V/bias come straight from global (L2-resident
// via the R4 2D swizzle). R5: loads batched per head (see header comment).
__global__ __launch_bounds__(256, 3) void attn_kernel(
    const float* __restrict__ gs,
    const u16* __restrict__ WqT, const float* __restrict__ bq,
    const u16* __restrict__ WpT, const float* __restrict__ bp,
    const u16* __restrict__ Kb, const u16* __restrict__ VbT,
    const u16* __restrict__ biasCT, float* __restrict__ out) {

    __shared__ u16 sXQ[TQ * SXS];  // gs tile -> Q (head-slab layout) -> x
    __shared__ u16 sP[TQ * SPS];   // P rows [q][n], wave-private 16-row slabs

    const int tid  = threadIdx.x;
    const int w    = tid >> 6;        // wave 0..3
    const int lane = tid & 63;
    const int l15  = tid & 15;
    const int quad = (tid >> 4) & 3;
    // R4 2D locality swizzle: xcd = bid&7 (HW round-robin), each XCD owns
    // b in [8*xcd, 8*xcd+8) for ALL qt; concurrent window = 8 b x ~12 qt ->
    // K/V+bias working set ~3MB fits the 4MB XCD L2.
    const int bid  = blockIdx.x;
    const int i8   = bid >> 3;           // 0..287 within XCD
    const int qt   = i8 >> 3;            // 0..35
    const int b    = (bid & 7) * 8 + (i8 & 7);
    const int q0   = qt * TQ;
    // 1/sqrt(30) * log2e : softmax runs in the exp2 domain
    const float SCALE = 0.18257418583505536f * 1.4426950408889634f;

    // ---- stage gs tile -> sXQ (bf16, zero pad cols 180..195) ----
    {
        const float4* src = (const float4*)(gs + (size_t)(b * NGS + q0) * DIM);
        for (int i = tid; i < TQ * 45; i += 256) {
            int row = i / 45, c = i - row * 45;
            float4 g = src[row * 45 + c];
            *(uint2*)&sXQ[row * SXS + c * 4] =
                make_uint2(cvt_pk_bf16(g.x, g.y), cvt_pk_bf16(g.z, g.w));
        }
        for (int i = tid; i < TQ * 16; i += 256)
            sXQ[(i >> 4) * SXS + 180 + (i & 15)] = 0;
    }
    __syncthreads();

    // ---- Q-proj: q = (gs @ Wq + bq)*scale. Accumulate in regs, then
    //      overwrite the (dead) gs tile with Q in 32-padded head-slab cols.
    v4f qacc[12];
#pragma unroll
    for (int i = 0; i < 12; ++i) qacc[i] = (v4f){0.f, 0.f, 0.f, 0.f};
    for (int kt = 0; kt < 6; ++kt) {
        v8s A[4];
#pragma unroll
        for (int m = 0; m < 4; ++m)
            A[m] = *(const v8s*)&sXQ[(16 * m + l15) * SXS + kt * 32 + quad * 8];
#pragma unroll
        for (int jj = 0; jj < 3; ++jj) {
            v8s B = *(const v8s*)&WqT[(size_t)((3 * w + jj) * 16 + l15) * WPAD +
                                      kt * 32 + quad * 8];
#pragma unroll
            for (int m = 0; m < 4; ++m)
                qacc[jj * 4 + m] = __builtin_amdgcn_mfma_f32_16x16x32_bf16(
                    A[m], B, qacc[jj * 4 + m], 0, 0, 0);
        }
    }
    __syncthreads();   // all waves done READING gs before Q overwrites it
#pragma unroll
    for (int jj = 0; jj < 3; ++jj) {
        int j = (3 * w + jj) * 16 + l15;
        if (j < DIM) {
            int h = j / HD;
            int pos = j + 2 * h;          // 32-padded head-slab column
            float bqj = bq[j];
#pragma unroll
            for (int m = 0; m < 4; ++m)
#pragma unroll
                for (int r = 0; r < 4; ++r) {
                    float v = (qacc[jj * 4 + m][r] + bqj) * SCALE;
                    sXQ[(16 * m + quad * 4 + r) * SXS + pos] =
                        (u16)cvt_pk_bf16(v, v);
                }
        }
    }
    // zero Q pad cols d=30,31 of every head slab
    for (int i = tid; i < TQ * 12; i += 256) {
        int row = i / 12, c = i - row * 12;
        sXQ[row * SXS + (c >> 1) * 32 + 30 + (c & 1)] = 0;
    }
    __syncthreads();

    // ---- per-head attention (no barriers inside) ----
    for (int h = 0; h < HEADS; ++h) {
        const u16* kp = Kb  + (size_t)(b * HEADS + h) * KB_STRIDE;
        const u16* vp = VbT + (size_t)(b * HEADS + h) * VB_STRIDE;

        // Q B-fragment: own q rows (16w+l15), this head's 32-col slab
        v8s qa = *(const v8s*)&sXQ[(16 * w + l15) * SXS + h * 32 + quad * 8];

        // ---- R5: batch-issue ALL QK-side loads (9 bias + 9 K) ----
        const u16* bgt = biasCT +
            ((size_t)((h * 144 + (qt * 4 + w)) * 9) * 256) + lane * 4;
        uint2 bb[9];
#pragma unroll
        for (int t = 0; t < 9; ++t) bb[t] = *(const uint2*)(bgt + t * 256);
        v8s kb[9];
#pragma unroll
        for (int t = 0; t < 9; ++t)
            kb[t] = *(const v8s*)&kp[(16 * t + l15) * KROW + quad * 8];

        // S^T = K · Q^T + bias^T : A = K rows (lane=n), B = Q (lane=q col).
        // C tile t: row n=16t+quad*4+r, col q=16w+l15.
        v4f la[9];
#pragma unroll
        for (int t = 0; t < 9; ++t) {
            la[t][0] = bf2f((u16)(bb[t].x & 0xffff));
            la[t][1] = bf2f((u16)(bb[t].x >> 16));
            la[t][2] = bf2f((u16)(bb[t].y & 0xffff));
            la[t][3] = bf2f((u16)(bb[t].y >> 16));
        }
#pragma unroll
        for (int t = 0; t < 9; ++t)
            la[t] = __builtin_amdgcn_mfma_f32_16x16x32_bf16(kb[t], qa, la[t], 0, 0, 0);

        // ---- R5: issue all V loads BEFORE softmax (latency hides under it)
        v8s va0[5], va1[5];
#pragma unroll
        for (int kt = 0; kt < 5; ++kt) {
            // skip lanes (kt==4, quad>=2) load a safe dummy row; their pa
            // (MFMA B k-slice) is zero, so the product contribution is zero.
            int co = (kt == 4 && quad >= 2) ? 0 : kt * 32 + quad * 8;
            va0[kt] = *(const v8s*)&vp[l15 * VROW + co];
            va1[kt] = *(const v8s*)&vp[(16 + l15) * VROW + co];
        }

        // softmax (exp2 domain): all 36 values in this lane share q=16w+l15;
        // quads hold disjoint n -> reduce across quads with xor 16,32 only.
        float m = la[0][0];
#pragma unroll
        for (int t = 0; t < 9; ++t)
#pragma unroll
            for (int r = 0; r < 4; ++r) m = fmaxf(m, la[t][r]);
        m = fmaxf(m, __shfl_xor(m, 16));
        m = fmaxf(m, __shfl_xor(m, 32));
        float s = 0.f;
#pragma unroll
        for (int t = 0; t < 9; ++t)
#pragma unroll
            for (int r = 0; r < 4; ++r) {
                la[t][r] = __builtin_amdgcn_exp2f(la[t][r] - m);
                s += la[t][r];
            }
        s += __shfl_xor(s, 16);
        s += __shfl_xor(s, 32);
        float inv = 1.f / s;   // applied to x outputs, not to P

        // P (UNNORMALIZED) -> own 16-row slab of sP, b64 per lane
#pragma unroll
        for (int t = 0; t < 9; ++t)
            *(uint2*)&sP[(16 * w + l15) * SPS + 16 * t + quad * 4] =
                make_uint2(cvt_pk_bf16(la[t][0], la[t][1]),
                           cvt_pk_bf16(la[t][2], la[t][3]));

        // x^T = V^T · P^T : A = V^T rows (lane=d), B = P rows (lane=q col).
        // k covers n=0..159; the n=144..159 half (kt==4, quad>=2) is zeroed
        // via zero pa regs (sP cols >=144 unwritten; VbT rows end at n=144).
        v4f x0 = (v4f){0.f, 0.f, 0.f, 0.f}, x1 = x0;
#pragma unroll
        for (int kt = 0; kt < 5; ++kt) {
            v8s pa = (v8s){0, 0, 0, 0, 0, 0, 0, 0};
            if (!(kt == 4 && quad >= 2))
                pa = *(const v8s*)&sP[(16 * w + l15) * SPS + kt * 32 + quad * 8];
            x0 = __builtin_amdgcn_mfma_f32_16x16x32_bf16(va0[kt], pa, x0, 0, 0, 0);
            x1 = __builtin_amdgcn_mfma_f32_16x16x32_bf16(va1[kt], pa, x1, 0, 0, 0);
        }
        // x^T C tile: row d=quad*4+r (tile0) / 16+quad*4+r (tile1), col q=l15.
        // Normalize by inv here (8 muls instead of 36 on P).
        v4f y0, y1;
#pragma unroll
        for (int r = 0; r < 4; ++r) { y0[r] = x0[r] * inv; y1[r] = x1[r] * inv; }
        *(uint2*)&sXQ[(16 * w + l15) * SXS + h * 32 + quad * 4]      = pack4(y0);
        *(uint2*)&sXQ[(16 * w + l15) * SXS + h * 32 + 16 + quad * 4] = pack4(y1);
    }
    __syncthreads();   // x rows are read cross-wave by out-proj

    // ---- out-proj: out = x @ Wp + bp (WpT is in matching 32-padded k-layout)
    {
        v4f acc[12];
#pragma unroll
        for (int i = 0; i < 12; ++i) acc[i] = (v4f){0.f, 0.f, 0.f, 0.f};
        for (int kt = 0; kt < 6; ++kt) {
            v8s A[4];
#pragma unroll
            for (int m = 0; m < 4; ++m)
                A[m] = *(const v8s*)&sXQ[(16 * m + l15) * SXS + kt * 32 + quad * 8];
#pragma unroll
            for (int jj = 0; jj < 3; ++jj) {
                v8s B = *(const v8s*)&WpT[(size_t)((3 * w + jj) * 16 + l15) * WPAD +
                                          kt * 32 + quad * 8];
#pragma unroll
                for (int m = 0; m < 4; ++m)
                    acc[jj * 4 + m] = __builtin_amdgcn_mfma_f32_16x16x32_bf16(
                        A[m], B, acc[jj * 4 + m], 0, 0, 0);
            }
        }
#pragma unroll
        for (int jj = 0; jj < 3; ++jj) {
            int j = (3 * w + jj) * 16 + l15;
            if (j < DIM) {
                float bpj = bp[j];
#pragma unroll
                for (int m = 0; m < 4; ++m)
#pragma unroll
                    for (int r = 0; r < 4; ++r)
                        out[(size_t)(b * NGS + q0 + 16 * m + quad * 4 + r) * DIM + j] =
                            acc[jj * 4 + m][r] + bpj;
            }
        }
    }
}

// ---------------------------------------------------------------------------
extern "C" void kernel_launch(void* const* d_in, const int* in_sizes, int n_in,
                              void* d_out, int out_size, void* d_ws, size_t ws_size,
                              hipStream_t stream) {
    const float* gs    = (const float*)d_in[0];
    const float* feat  = (const float*)d_in[1];
    const float* Wq    = (const float*)d_in[2];
    const float* bq    = (const float*)d_in[3];
    const float* Wk    = (const float*)d_in[4];
    const float* bk    = (const float*)d_in[5];
    const float* Wv    = (const float*)d_in[6];
    const float* bv    = (const float*)d_in[7];
    const float* Wp    = (const float*)d_in[8];
    const float* bp    = (const float*)d_in[9];
    const float* table = (const float*)d_in[10];
    const int*   rpi   = (const int*)d_in[11];
    float* out = (float*)d_out;

    // ws layout (u16 units): WqT | WpT | Kb | VbT | biasCT  (~12.1 MB)
    u16* WqT    = (u16*)d_ws;
    u16* WpT    = WqT + WPAD * WPAD;
    u16* Kb     = WpT + WPAD * WPAD;
    u16* VbT    = Kb  + (size_t)BATCH * HEADS * KB_STRIDE;
    u16* biasCT = VbT + (size_t)BATCH * HEADS * VB_STRIDE;

    // zero K pads (d=30..39) and V pad rows (d=30,31): MFMA reads them
    size_t zero_bytes = (size_t)BATCH * HEADS * (KB_STRIDE + VB_STRIDE) * sizeof(u16);
    hipMemsetAsync(Kb, 0, zero_bytes, stream);

    wt_prep_kernel<<<dim3(2 * WPAD * WPAD / 256), dim3(256), 0, stream>>>(Wq, Wp, WqT, WpT);
    gather_bias_kernel<<<dim3(HEADS * 144 * 9 * 64 / 256), dim3(256), 0, stream>>>(
        table, rpi, biasCT);
    kv_proj_kernel<<<dim3(BATCH * 9), dim3(256), 0, stream>>>(feat, Wk, bk, Wv, bv, Kb, VbT);
    attn_kernel<<<dim3(BATCH * QT), dim3(256), 0, stream>>>(
        gs, WqT, bq, WpT, bp, Kb, VbT, biasCT, out);
}

// Round 7
// 365.269 us; speedup vs baseline: 1.1941x; 1.0315x over previous
//
#include <hip/hip_runtime.h>

// Problem constants
#define DIM   180
#define HEADS 6
#define HD    30
#define NKEY  144
#define NGS   2304
#define BATCH 64
#define TQ    64
#define QT    36                // q-tiles (2304/64)
#define WPAD  192               // padded model dim (6 k-tiles of 32)
#define SXS   200               // sXQ row stride u16 (400 B, rows 16B-aligned)
#define SPS   144               // sP row stride u16 (288 B; 4-way bank alias, ok)
#define KROW  32                // Kb row stride u16 (DENSE 64 B rows -> linear LDS stage)
#define VROW  144               // VbT row stride u16 (288 B, dense slab)
#define KB_STRIDE (NKEY * KROW) // 4608 u16 per (b,h) = 9216 B dense
#define VB_STRIDE (32 * VROW)   // 4608 u16 per (b,h) = 9216 B dense

typedef unsigned short u16;
typedef short v8s __attribute__((ext_vector_type(8)));   // 8 x bf16 MFMA operand
typedef float v4f __attribute__((ext_vector_type(4)));   // 4 x f32 MFMA acc

__device__ __forceinline__ float bf2f(u16 u) {
    union { unsigned int i; float f; } w; w.i = ((unsigned int)u) << 16; return w.f;
}
__device__ __forceinline__ u16 f2bf(float f) {
    union { float f; unsigned int i; } w; w.f = f;
    unsigned int r = w.i + 0x7fffu + ((w.i >> 16) & 1u);
    return (u16)(r >> 16);
}
// single-instruction RNE f32->bf16 pair (R5)
__device__ __forceinline__ unsigned cvt_pk_bf16(float lo, float hi) {
    unsigned r;
    asm("v_cvt_pk_bf16_f32 %0, %1, %2" : "=v"(r) : "v"(lo), "v"(hi));
    return r;
}
__device__ __forceinline__ uint2 pack4(const v4f& x) {
    return make_uint2(cvt_pk_bf16(x[0], x[1]), cvt_pk_bf16(x[2], x[3]));
}
// R7: async global->LDS copy, 16B per lane, linear LDS dest (wave-uniform
// base + lane*16 — our chunk index i = tid + 256*k gives exactly that).
__device__ __forceinline__ void gload_lds16(const u16* g, u16* l) {
    __builtin_amdgcn_global_load_lds(
        (const __attribute__((address_space(1))) unsigned int*)g,
        (__attribute__((address_space(3))) unsigned int*)l, 16, 0, 0);
}

// ---------------------------------------------------------------------------
// R7 THEORY: the kernel is L1/TA-bandwidth-bound (~93% of the 45Kcy block
// wall is per-CU L1 bytes; MfmaUtil 9.5% matches the MFMA-issue fraction).
// All 4 waves loaded IDENTICAL K (9KB/head) and V (10KB/head) copies from
// global. Fix: stage K,V once per block into LDS (global_load_lds, dense
// slabs), cutting ~350KB/block of L1 traffic. sK overlays sP (K dead after
// QK, P written after) so LDS stays 53248 B = 3 blocks/CU. All sync via
// __syncthreads() barrier drains — no manual vmcnt (R6's failure class).
// ---------------------------------------------------------------------------

// Weight prep: WqT[j][k] = Wq[k][j]; WpT[j][k'] with k' = h*32+dd (32-padded
// head-slab k-layout matching where attn leaves x in LDS), k = h*30+dd.
__global__ __launch_bounds__(256) void wt_prep_kernel(
    const float* __restrict__ Wq, const float* __restrict__ Wp,
    u16* __restrict__ WqT, u16* __restrict__ WpT) {
    int idx = blockIdx.x * 256 + threadIdx.x;        // < 2*192*192
    int sel = idx >= WPAD * WPAD;
    int rr  = sel ? idx - WPAD * WPAD : idx;
    int j = rr / WPAD, k = rr - j * WPAD;
    float v;
    if (!sel) {
        v = (j < DIM && k < DIM) ? Wq[k * DIM + j] : 0.f;
        WqT[j * WPAD + k] = f2bf(v);
    } else {
        int h = k >> 5, dd = k & 31;
        v = (j < DIM && dd < HD) ? Wp[(h * HD + dd) * DIM + j] : 0.f;
        WpT[j * WPAD + k] = f2bf(v);
    }
}

// ---------------------------------------------------------------------------
// Bias pre-gather in S^T C-fragment order: tile (h, g=q/16, t=n/16); lane
// (l15,quad) holds rows n=16t+quad*4+r, col q=16g+l15. Values pre-scaled by
// log2e (softmax runs in the exp2 domain).
__global__ __launch_bounds__(256) void gather_bias_kernel(
    const float* __restrict__ table, const int* __restrict__ rpi,
    u16* __restrict__ biasCT) {
    const float LOG2E = 1.4426950408889634f;
    int i = blockIdx.x * 256 + threadIdx.x;          // < 7776*64 = 497664
    int lane = i & 63;
    int tile = i >> 6;
    int t = tile % 9;
    int rem = tile / 9;
    int g = rem % 144;
    int h = rem / 144;
    int q  = 16 * g + (lane & 15);
    int n0 = 16 * t + (lane >> 4) * 4;
    const int4 rr = *(const int4*)&rpi[q * NKEY + n0];
    unsigned lo = (unsigned)f2bf(table[rr.x * HEADS + h] * LOG2E) |
                  ((unsigned)f2bf(table[rr.y * HEADS + h] * LOG2E) << 16);
    unsigned hi = (unsigned)f2bf(table[rr.z * HEADS + h] * LOG2E) |
                  ((unsigned)f2bf(table[rr.w * HEADS + h] * LOG2E) << 16);
    ((uint2*)biasCT)[i] = make_uint2(lo, hi);
}

// ---------------------------------------------------------------------------
// K/V projection -> bf16 fragment-ready global layouts (both DENSE slabs):
//   Kb [b][h][n][32]   (d pad 30,31 = 0 via memset)  -- 9216 B per (b,h)
//   VbT[b][h][d][144]  (d rows 30,31 = 0 via memset) -- 9216 B per (b,h)
__global__ __launch_bounds__(256) void kv_proj_kernel(
    const float* __restrict__ feat,
    const float* __restrict__ Wk, const float* __restrict__ bk,
    const float* __restrict__ Wv, const float* __restrict__ bv,
    u16* __restrict__ Kb, u16* __restrict__ VbT) {
    __shared__ float sF[16 * DIM];
    int b  = blockIdx.x / 9;
    int n0 = (blockIdx.x % 9) * 16;
    int tid = threadIdx.x;
    {
        const float4* src = (const float4*)(feat + (size_t)(b * NKEY + n0) * DIM);
        float4* dst = (float4*)sF;
        for (int i = tid; i < 16 * 45; i += 256) dst[i] = src[i];
    }
    __syncthreads();
    int j = tid;
    if (j < DIM) {
        float ak[16], av[16];
#pragma unroll
        for (int r = 0; r < 16; ++r) { ak[r] = 0.f; av[r] = 0.f; }
        const float4* sF4 = (const float4*)sF;
        for (int kc = 0; kc < 45; ++kc) {
            int kk = kc * 4;
            float wk0 = Wk[(kk + 0) * DIM + j], wk1 = Wk[(kk + 1) * DIM + j];
            float wk2 = Wk[(kk + 2) * DIM + j], wk3 = Wk[(kk + 3) * DIM + j];
            float wv0 = Wv[(kk + 0) * DIM + j], wv1 = Wv[(kk + 1) * DIM + j];
            float wv2 = Wv[(kk + 2) * DIM + j], wv3 = Wv[(kk + 3) * DIM + j];
#pragma unroll
            for (int r = 0; r < 16; ++r) {
                float4 g = sF4[r * 45 + kc];
                ak[r] = fmaf(g.x, wk0, ak[r]); ak[r] = fmaf(g.y, wk1, ak[r]);
                ak[r] = fmaf(g.z, wk2, ak[r]); ak[r] = fmaf(g.w, wk3, ak[r]);
                av[r] = fmaf(g.x, wv0, av[r]); av[r] = fmaf(g.y, wv1, av[r]);
                av[r] = fmaf(g.z, wv2, av[r]); av[r] = fmaf(g.w, wv3, av[r]);
            }
        }
        int h = j / HD, d = j - HD * h;
        u16* kp = Kb  + (size_t)(b * HEADS + h) * KB_STRIDE;
        u16* vp = VbT + (size_t)(b * HEADS + h) * VB_STRIDE;
        float bkj = bk[j], bvj = bv[j];
#pragma unroll
        for (int r = 0; r < 16; ++r) {
            kp[(n0 + r) * KROW + d] = f2bf(ak[r] + bkj);
            vp[d * VROW + n0 + r]   = f2bf(av[r] + bvj);
        }
    }
}

// ---------------------------------------------------------------------------
// Fused MFMA attention. One block = (batch, 64-query tile), 4 waves.
// LDS: sXQ 25600 + sV 9216 + sPK 18432 = 53248 B (= 160K/3) -> 3 blocks/CU.
// Per head: [bar] stage K,V via global_load_lds (once per BLOCK — kills the
// 4x redundant per-wave K/V global loads) [bar] QK from sK [bar] softmax,
// P overlays sK, PV from sPK/sV. Bias stays per-wave global (w-specific).
__global__ __launch_bounds__(256, 3) void attn_kernel(
    const float* __restrict__ gs,
    const u16* __restrict__ WqT, const float* __restrict__ bq,
    const u16* __restrict__ WpT, const float* __restrict__ bp,
    const u16* __restrict__ Kb, const u16* __restrict__ VbT,
    const u16* __restrict__ biasCT, float* __restrict__ out) {

    __shared__ u16 sXQ[TQ * SXS];   // gs tile -> Q (head-slab) -> x   25600 B
    __shared__ u16 sV[32 * VROW];   // V(h) [d][n]                      9216 B
    __shared__ u16 sPK[TQ * SPS];   // P rows [q][n]; first 9216 B = sK[n][32]

    const int tid  = threadIdx.x;
    const int w    = tid >> 6;        // wave 0..3
    const int lane = tid & 63;
    const int l15  = tid & 15;
    const int quad = (tid >> 4) & 3;
    // R4 2D locality swizzle: each XCD owns 8 batches for all qt.
    const int bid  = blockIdx.x;
    const int i8   = bid >> 3;           // 0..287 within XCD
    const int qt   = i8 >> 3;            // 0..35
    const int b    = (bid & 7) * 8 + (i8 & 7);
    const int q0   = qt * TQ;
    // 1/sqrt(30) * log2e : softmax runs in the exp2 domain
    const float SCALE = 0.18257418583505536f * 1.4426950408889634f;

    // ---- stage gs tile -> sXQ (bf16, zero pad cols 180..195) ----
    {
        const float4* src = (const float4*)(gs + (size_t)(b * NGS + q0) * DIM);
        for (int i = tid; i < TQ * 45; i += 256) {
            int row = i / 45, c = i - row * 45;
            float4 g = src[row * 45 + c];
            *(uint2*)&sXQ[row * SXS + c * 4] =
                make_uint2(cvt_pk_bf16(g.x, g.y), cvt_pk_bf16(g.z, g.w));
        }
        for (int i = tid; i < TQ * 16; i += 256)
            sXQ[(i >> 4) * SXS + 180 + (i & 15)] = 0;
    }
    __syncthreads();

    // ---- Q-proj: q = (gs @ Wq + bq)*scale ----
    v4f qacc[12];
#pragma unroll
    for (int i = 0; i < 12; ++i) qacc[i] = (v4f){0.f, 0.f, 0.f, 0.f};
    for (int kt = 0; kt < 6; ++kt) {
        v8s A[4];
#pragma unroll
        for (int m = 0; m < 4; ++m)
            A[m] = *(const v8s*)&sXQ[(16 * m + l15) * SXS + kt * 32 + quad * 8];
#pragma unroll
        for (int jj = 0; jj < 3; ++jj) {
            v8s B = *(const v8s*)&WqT[(size_t)((3 * w + jj) * 16 + l15) * WPAD +
                                      kt * 32 + quad * 8];
#pragma unroll
            for (int m = 0; m < 4; ++m)
                qacc[jj * 4 + m] = __builtin_amdgcn_mfma_f32_16x16x32_bf16(
                    A[m], B, qacc[jj * 4 + m], 0, 0, 0);
        }
    }
    __syncthreads();   // all waves done READING gs before Q overwrites it
#pragma unroll
    for (int jj = 0; jj < 3; ++jj) {
        int j = (3 * w + jj) * 16 + l15;
        if (j < DIM) {
            int h = j / HD;
            int pos = j + 2 * h;          // 32-padded head-slab column
            float bqj = bq[j];
#pragma unroll
            for (int m = 0; m < 4; ++m)
#pragma unroll
                for (int r = 0; r < 4; ++r) {
                    float v = (qacc[jj * 4 + m][r] + bqj) * SCALE;
                    sXQ[(16 * m + quad * 4 + r) * SXS + pos] =
                        (u16)cvt_pk_bf16(v, v);
                }
        }
    }
    // zero Q pad cols d=30,31 of every head slab
    for (int i = tid; i < TQ * 12; i += 256) {
        int row = i / 12, c = i - row * 12;
        sXQ[row * SXS + (c >> 1) * 32 + 30 + (c & 1)] = 0;
    }
    __syncthreads();   // also serves as bar0 for head 0's stage

    // ---- per-head attention ----
    for (int h = 0; h < HEADS; ++h) {
        if (h) __syncthreads();          // bar0: prev PV done reading sPK/sV

        // stage K(h), V(h) once per block: dense 9216B slabs, 576 x 16B
        // chunks each, linear LDS dest (global_load_lds lane rule satisfied)
        {
            const u16* kg = Kb  + (size_t)(b * HEADS + h) * KB_STRIDE;
            const u16* vg = VbT + (size_t)(b * HEADS + h) * VB_STRIDE;
            for (int i = tid; i < 576; i += 256) gload_lds16(kg + i * 8, sPK + i * 8);
            for (int i = tid; i < 576; i += 256) gload_lds16(vg + i * 8, sV + i * 8);
        }
        // bias: per-wave (w-specific), plain loads, consumed after bar1
        const u16* bgt = biasCT +
            ((size_t)((h * 144 + (qt * 4 + w)) * 9) * 256) + lane * 4;
        uint2 bb[9];
#pragma unroll
        for (int t = 0; t < 9; ++t) bb[t] = *(const uint2*)(bgt + t * 256);

        // Q B-fragment: own q rows (16w+l15), this head's 32-col slab
        v8s qa = *(const v8s*)&sXQ[(16 * w + l15) * SXS + h * 32 + quad * 8];

        __syncthreads();   // bar1: stage complete (barrier drains vmcnt)

        // S^T = K · Q^T + bias^T ; C tile t: row n=16t+quad*4+r, col 16w+l15
        v4f la[9];
#pragma unroll
        for (int t = 0; t < 9; ++t) {
            la[t][0] = bf2f((u16)(bb[t].x & 0xffff));
            la[t][1] = bf2f((u16)(bb[t].x >> 16));
            la[t][2] = bf2f((u16)(bb[t].y & 0xffff));
            la[t][3] = bf2f((u16)(bb[t].y >> 16));
        }
#pragma unroll
        for (int t = 0; t < 9; ++t) {
            v8s kb = *(const v8s*)&sPK[(16 * t + l15) * KROW + quad * 8];
            la[t] = __builtin_amdgcn_mfma_f32_16x16x32_bf16(kb, qa, la[t], 0, 0, 0);
        }

        __syncthreads();   // bar2: all waves done reading sK; P may overwrite

        // softmax (exp2 domain): quads hold disjoint n -> xor 16,32 reduce
        float m = la[0][0];
#pragma unroll
        for (int t = 0; t < 9; ++t)
#pragma unroll
            for (int r = 0; r < 4; ++r) m = fmaxf(m, la[t][r]);
        m = fmaxf(m, __shfl_xor(m, 16));
        m = fmaxf(m, __shfl_xor(m, 32));
        float s = 0.f;
#pragma unroll
        for (int t = 0; t < 9; ++t)
#pragma unroll
            for (int r = 0; r < 4; ++r) {
                la[t][r] = __builtin_amdgcn_exp2f(la[t][r] - m);
                s += la[t][r];
            }
        s += __shfl_xor(s, 16);
        s += __shfl_xor(s, 32);
        float inv = 1.f / s;   // applied to x outputs, not to P

        // P (UNNORMALIZED) -> own 16-row slab of sPK, b64 per lane
#pragma unroll
        for (int t = 0; t < 9; ++t)
            *(uint2*)&sPK[(16 * w + l15) * SPS + 16 * t + quad * 4] =
                make_uint2(cvt_pk_bf16(la[t][0], la[t][1]),
                           cvt_pk_bf16(la[t][2], la[t][3]));

        // x^T = V^T · P^T : A = V^T rows from sV (lane=d), B = P rows.
        // k covers n=0..159; (kt==4, quad>=2) handled via zero pa regs.
        v4f x0 = (v4f){0.f, 0.f, 0.f, 0.f}, x1 = x0;
#pragma unroll
        for (int kt = 0; kt < 5; ++kt) {
            v8s pa = (v8s){0, 0, 0, 0, 0, 0, 0, 0};
            v8s a0 = pa, a1 = pa;
            if (!(kt == 4 && quad >= 2)) {
                int co = kt * 32 + quad * 8;
                pa = *(const v8s*)&sPK[(16 * w + l15) * SPS + co];
                a0 = *(const v8s*)&sV[l15 * VROW + co];
                a1 = *(const v8s*)&sV[(16 + l15) * VROW + co];
            }
            x0 = __builtin_amdgcn_mfma_f32_16x16x32_bf16(a0, pa, x0, 0, 0, 0);
            x1 = __builtin_amdgcn_mfma_f32_16x16x32_bf16(a1, pa, x1, 0, 0, 0);
        }
        // x^T C tile -> dead Q slab h; normalize by inv here (8 muls).
        v4f y0, y1;
#pragma unroll
        for (int r = 0; r < 4; ++r) { y0[r] = x0[r] * inv; y1[r] = x1[r] * inv; }
        *(uint2*)&sXQ[(16 * w + l15) * SXS + h * 32 + quad * 4]      = pack4(y0);
        *(uint2*)&sXQ[(16 * w + l15) * SXS + h * 32 + 16 + quad * 4] = pack4(y1);
    }
    __syncthreads();   // x rows are read cross-wave by out-proj

    // ---- out-proj: out = x @ Wp + bp ----
    {
        v4f acc[12];
#pragma unroll
        for (int i = 0; i < 12; ++i) acc[i] = (v4f){0.f, 0.f, 0.f, 0.f};
        for (int kt = 0; kt < 6; ++kt) {
            v8s A[4];
#pragma unroll
            for (int m = 0; m < 4; ++m)
                A[m] = *(const v8s*)&sXQ[(16 * m + l15) * SXS + kt * 32 + quad * 8];
#pragma unroll
            for (int jj = 0; jj < 3; ++jj) {
                v8s B = *(const v8s*)&WpT[(size_t)((3 * w + jj) * 16 + l15) * WPAD +
                                          kt * 32 + quad * 8];
#pragma unroll
                for (int m = 0; m < 4; ++m)
                    acc[jj * 4 + m] = __builtin_amdgcn_mfma_f32_16x16x32_bf16(
                        A[m], B, acc[jj * 4 + m], 0, 0, 0);
            }
        }
#pragma unroll
        for (int jj = 0; jj < 3; ++jj) {
            int j = (3 * w + jj) * 16 + l15;
            if (j < DIM) {
                float bpj = bp[j];
#pragma unroll
                for (int m = 0; m < 4; ++m)
#pragma unroll
                    for (int r = 0; r < 4; ++r)
                        out[(size_t)(b * NGS + q0 + 16 * m + quad * 4 + r) * DIM + j] =
                            acc[jj * 4 + m][r] + bpj;
            }
        }
    }
}

// ---------------------------------------------------------------------------
extern "C" void kernel_launch(void* const* d_in, const int* in_sizes, int n_in,
                              void* d_out, int out_size, void* d_ws, size_t ws_size,
                              hipStream_t stream) {
    const float* gs    = (const float*)d_in[0];
    const float* feat  = (const float*)d_in[1];
    const float* Wq    = (const float*)d_in[2];
    const float* bq    = (const float*)d_in[3];
    const float* Wk    = (const float*)d_in[4];
    const float* bk    = (const float*)d_in[5];
    const float* Wv    = (const float*)d_in[6];
    const float* bv    = (const float*)d_in[7];
    const float* Wp    = (const float*)d_in[8];
    const float* bp    = (const float*)d_in[9];
    const float* table = (const float*)d_in[10];
    const int*   rpi   = (const int*)d_in[11];
    float* out = (float*)d_out;

    // ws layout (u16 units): WqT | WpT | Kb | VbT | biasCT
    u16* WqT    = (u16*)d_ws;
    u16* WpT    = WqT + WPAD * WPAD;
    u16* Kb     = WpT + WPAD * WPAD;
    u16* VbT    = Kb  + (size_t)BATCH * HEADS * KB_STRIDE;
    u16* biasCT = VbT + (size_t)BATCH * HEADS * VB_STRIDE;

    // zero K pads (d=30,31) and V pad rows (d=30,31): MFMA reads them
    size_t zero_bytes = (size_t)BATCH * HEADS * (KB_STRIDE + VB_STRIDE) * sizeof(u16);
    hipMemsetAsync(Kb, 0, zero_bytes, stream);

    wt_prep_kernel<<<dim3(2 * WPAD * WPAD / 256), dim3(256), 0, stream>>>(Wq, Wp, WqT, WpT);
    gather_bias_kernel<<<dim3(HEADS * 144 * 9 * 64 / 256), dim3(256), 0, stream>>>(
        table, rpi, biasCT);
    kv_proj_kernel<<<dim3(BATCH * 9), dim3(256), 0, stream>>>(feat, Wk, bk, Wv, bv, Kb, VbT);
    attn_kernel<<<dim3(BATCH * QT), dim3(256), 0, stream>>>(
        gs, WqT, bq, WpT, bp, Kb, VbT, biasCT, out);
}

// Round 8
// 361.581 us; speedup vs baseline: 1.2063x; 1.0102x over previous
//
#include <hip/hip_runtime.h>

// Problem constants
#define DIM   180
#define HEADS 6
#define HD    30
#define NKEY  144
#define NGS   2304
#define BATCH 64
#define TQ    64
#define QT    36                // q-tiles (2304/64)
#define WPAD  192               // padded model dim (6 k-tiles of 32)
#define SXS   200               // sXQ row stride u16 (400 B, rows 16B-aligned, 2-way banks)
#define KROW  32                // Kb row stride u16 (DENSE 64 B rows, XOR-swizzled cols)
#define VROW  152               // VbT row stride u16 (304 B -> 2-way-conflict sV reads)
#define KB_STRIDE (NKEY * KROW) // 4608 u16 per (b,h) = 9216 B dense
#define VB_STRIDE (32 * VROW)   // 4864 u16 per (b,h) = 9728 B dense

typedef unsigned short u16;
typedef short v8s __attribute__((ext_vector_type(8)));   // 8 x bf16 MFMA operand
typedef float v4f __attribute__((ext_vector_type(4)));   // 4 x f32 MFMA acc

__device__ __forceinline__ float bf2f(u16 u) {
    union { unsigned int i; float f; } w; w.i = ((unsigned int)u) << 16; return w.f;
}
__device__ __forceinline__ u16 f2bf(float f) {
    union { float f; unsigned int i; } w; w.f = f;
    unsigned int r = w.i + 0x7fffu + ((w.i >> 16) & 1u);
    return (u16)(r >> 16);
}
// single-instruction RNE f32->bf16 pair (R5)
__device__ __forceinline__ unsigned cvt_pk_bf16(float lo, float hi) {
    unsigned r;
    asm("v_cvt_pk_bf16_f32 %0, %1, %2" : "=v"(r) : "v"(lo), "v"(hi));
    return r;
}
__device__ __forceinline__ uint2 pack4(const v4f& x) {
    return make_uint2(cvt_pk_bf16(x[0], x[1]), cvt_pk_bf16(x[2], x[3]));
}
// async global->LDS copy, 16B per lane, linear LDS dest (R7, verified)
__device__ __forceinline__ void gload_lds16(const u16* g, u16* l) {
    __builtin_amdgcn_global_load_lds(
        (const __attribute__((address_space(1))) unsigned int*)g,
        (__attribute__((address_space(3))) unsigned int*)l, 16, 0, 0);
}

// ---------------------------------------------------------------------------
// R8: critical-path round. Wall model closed: 42Kcy/block-slot = 14Kcy path
// x 3 rounds. Changes: (1) sK double-buffered, staged AFTER the PV barrier
// -> stage latency off-path; (2) P in registers via R1's proven key-sigma +
// permlane32_swap (sP LDS round-trip gone); (3) 2 barriers/head (was 3 +
// waits); (4) tree max/sum reductions (depth 6 vs 36 serial); (5) sK source
// XOR-swizzle (8-way -> 4-way bank) and VROW=152 (sV reads 2-way).
// KEY SIGMA (R1, proven correct): within every 16-key block of the S^T tile,
// C-row positions hold keys sigma=[0-3,8-11,4-7,12-15]. The quad-transpose
// of P between softmax and PV is then exactly swap(lane-bit5, reg-bit) =
// one v_permlane32_swap_b32 per dword pair. sigma applied to Kb rows
// (kv_proj) and biasCT rows (gather); V stays natural order.
// All waits are barrier drains — no manual vmcnt (R6's failure class).
// ---------------------------------------------------------------------------

// Weight prep: WqT[j][k] = Wq[k][j]; WpT[j][k'] with k' = h*32+dd (32-padded
// head-slab k-layout matching where attn leaves x in LDS), k = h*30+dd.
__global__ __launch_bounds__(256) void wt_prep_kernel(
    const float* __restrict__ Wq, const float* __restrict__ Wp,
    u16* __restrict__ WqT, u16* __restrict__ WpT) {
    int idx = blockIdx.x * 256 + threadIdx.x;        // < 2*192*192
    int sel = idx >= WPAD * WPAD;
    int rr  = sel ? idx - WPAD * WPAD : idx;
    int j = rr / WPAD, k = rr - j * WPAD;
    float v;
    if (!sel) {
        v = (j < DIM && k < DIM) ? Wq[k * DIM + j] : 0.f;
        WqT[j * WPAD + k] = f2bf(v);
    } else {
        int h = k >> 5, dd = k & 31;
        v = (j < DIM && dd < HD) ? Wp[(h * HD + dd) * DIM + j] : 0.f;
        WpT[j * WPAD + k] = f2bf(v);
    }
}

// ---------------------------------------------------------------------------
// Bias pre-gather in S^T C-fragment order WITH key sigma (R1): tile
// (h, g=q/16, t=n/16); lane (l15,quad) holds C-rows 16t+quad*4+r carrying
// keys 16t+pg*4+r, pg = quad with bits swapped (0,2,1,3). col q=16g+l15.
// Values pre-scaled by log2e (softmax runs in exp2 domain).
__global__ __launch_bounds__(256) void gather_bias_kernel(
    const float* __restrict__ table, const int* __restrict__ rpi,
    u16* __restrict__ biasCT) {
    const float LOG2E = 1.4426950408889634f;
    int i = blockIdx.x * 256 + threadIdx.x;          // < 7776*64 = 497664
    int lane = i & 63;
    int tile = i >> 6;
    int t = tile % 9;
    int rem = tile / 9;
    int g = rem % 144;
    int h = rem / 144;
    int qd = (lane >> 4) & 3;
    int pg = ((qd & 1) << 1) | (qd >> 1);            // sigma group: 0,2,1,3
    int q  = 16 * g + (lane & 15);
    int n0 = 16 * t + pg * 4;
    const int4 rr = *(const int4*)&rpi[q * NKEY + n0];
    unsigned lo = (unsigned)f2bf(table[rr.x * HEADS + h] * LOG2E) |
                  ((unsigned)f2bf(table[rr.y * HEADS + h] * LOG2E) << 16);
    unsigned hi = (unsigned)f2bf(table[rr.z * HEADS + h] * LOG2E) |
                  ((unsigned)f2bf(table[rr.w * HEADS + h] * LOG2E) << 16);
    ((uint2*)biasCT)[i] = make_uint2(lo, hi);
}

// ---------------------------------------------------------------------------
// K/V projection -> bf16 fragment-ready global layouts (DENSE slabs):
//   Kb [b][h][n'][32]  n' = sigma(n), cols XOR-swizzled by (n'&3)
//                      (d pads = 0 via memset)        -- 9216 B per (b,h)
//   VbT[b][h][d][152]  natural key order (d rows 30,31 & col pads = 0)
__global__ __launch_bounds__(256) void kv_proj_kernel(
    const float* __restrict__ feat,
    const float* __restrict__ Wk, const float* __restrict__ bk,
    const float* __restrict__ Wv, const float* __restrict__ bv,
    u16* __restrict__ Kb, u16* __restrict__ VbT) {
    __shared__ float sF[16 * DIM];
    int b  = blockIdx.x / 9;
    int n0 = (blockIdx.x % 9) * 16;
    int tid = threadIdx.x;
    {
        const float4* src = (const float4*)(feat + (size_t)(b * NKEY + n0) * DIM);
        float4* dst = (float4*)sF;
        for (int i = tid; i < 16 * 45; i += 256) dst[i] = src[i];
    }
    __syncthreads();
    int j = tid;
    if (j < DIM) {
        float ak[16], av[16];
#pragma unroll
        for (int r = 0; r < 16; ++r) { ak[r] = 0.f; av[r] = 0.f; }
        const float4* sF4 = (const float4*)sF;
        for (int kc = 0; kc < 45; ++kc) {
            int kk = kc * 4;
            float wk0 = Wk[(kk + 0) * DIM + j], wk1 = Wk[(kk + 1) * DIM + j];
            float wk2 = Wk[(kk + 2) * DIM + j], wk3 = Wk[(kk + 3) * DIM + j];
            float wv0 = Wv[(kk + 0) * DIM + j], wv1 = Wv[(kk + 1) * DIM + j];
            float wv2 = Wv[(kk + 2) * DIM + j], wv3 = Wv[(kk + 3) * DIM + j];
#pragma unroll
            for (int r = 0; r < 16; ++r) {
                float4 g = sF4[r * 45 + kc];
                ak[r] = fmaf(g.x, wk0, ak[r]); ak[r] = fmaf(g.y, wk1, ak[r]);
                ak[r] = fmaf(g.z, wk2, ak[r]); ak[r] = fmaf(g.w, wk3, ak[r]);
                av[r] = fmaf(g.x, wv0, av[r]); av[r] = fmaf(g.y, wv1, av[r]);
                av[r] = fmaf(g.z, wv2, av[r]); av[r] = fmaf(g.w, wv3, av[r]);
            }
        }
        int h = j / HD, d = j - HD * h;
        u16* kp = Kb  + (size_t)(b * HEADS + h) * KB_STRIDE;
        u16* vp = VbT + (size_t)(b * HEADS + h) * VB_STRIDE;
        float bkj = bk[j], bvj = bv[j];
#pragma unroll
        for (int r = 0; r < 16; ++r) {
            // key n0+r -> row position n0+sigma(r) (sigma is an involution)
            int sr = ((r >> 2) == 1) ? r + 4 : ((r >> 2) == 2) ? r - 4 : r;
            int nn = n0 + sr;
            // XOR bank-swizzle: d-group (d>>3) stored at group (d>>3)^(nn&3)
            kp[nn * KROW + ((((d >> 3) ^ (nn & 3)) & 3) << 3) + (d & 7)] =
                f2bf(ak[r] + bkj);
            vp[d * VROW + n0 + r] = f2bf(av[r] + bvj);
        }
    }
}

// ---------------------------------------------------------------------------
// Fused MFMA attention. One block = (batch, 64-query tile), 4 waves.
// LDS: sXQ 25600 + sK dbuf 18432 + sV 9728 = 53760 B -> 3 blocks/CU.
// Head schedule (2 barriers/head, stages always off-path):
//   prologue: stage K0->sK[0], K1->sK[1], V0; bar
//   head h: QK from sK[h&1] -> softmax (trees) -> pack P in regs
//           barA (drains V(h), K(h+1) stages; all waves past QK(h))
//           PV from sV via permlane32_swap P-fragments -> x to sXQ slab
//           barB; issue stage K(h+2)->sK[h&1], V(h+1)->sV
__global__ __launch_bounds__(256, 3) void attn_kernel(
    const float* __restrict__ gs,
    const u16* __restrict__ WqT, const float* __restrict__ bq,
    const u16* __restrict__ WpT, const float* __restrict__ bp,
    const u16* __restrict__ Kb, const u16* __restrict__ VbT,
    const u16* __restrict__ biasCT, float* __restrict__ out) {

    __shared__ u16 sXQ[TQ * SXS];        // gs -> Q (head-slab) -> x  25600 B
    __shared__ u16 sK2[2 * NKEY * KROW]; // K double buffer          18432 B
    __shared__ u16 sV[32 * VROW];        // V(h) [d][n]               9728 B

    const int tid  = threadIdx.x;
    const int w    = tid >> 6;        // wave 0..3
    const int lane = tid & 63;
    const int l15  = tid & 15;
    const int quad = (tid >> 4) & 3;
    // R4 2D locality swizzle: each XCD owns 8 batches for all qt.
    const int bid  = blockIdx.x;
    const int i8   = bid >> 3;           // 0..287 within XCD
    const int qt   = i8 >> 3;            // 0..35
    const int b    = (bid & 7) * 8 + (i8 & 7);
    const int q0   = qt * TQ;
    // 1/sqrt(30) * log2e : softmax runs in the exp2 domain
    const float SCALE = 0.18257418583505536f * 1.4426950408889634f;

    // ---- stage gs tile -> sXQ (bf16, zero pad cols 180..195) ----
    {
        const float4* src = (const float4*)(gs + (size_t)(b * NGS + q0) * DIM);
        for (int i = tid; i < TQ * 45; i += 256) {
            int row = i / 45, c = i - row * 45;
            float4 g = src[row * 45 + c];
            *(uint2*)&sXQ[row * SXS + c * 4] =
                make_uint2(cvt_pk_bf16(g.x, g.y), cvt_pk_bf16(g.z, g.w));
        }
        for (int i = tid; i < TQ * 16; i += 256)
            sXQ[(i >> 4) * SXS + 180 + (i & 15)] = 0;
    }
    __syncthreads();

    // ---- Q-proj: q = (gs @ Wq + bq)*scale ----
    v4f qacc[12];
#pragma unroll
    for (int i = 0; i < 12; ++i) qacc[i] = (v4f){0.f, 0.f, 0.f, 0.f};
    for (int kt = 0; kt < 6; ++kt) {
        v8s A[4];
#pragma unroll
        for (int m = 0; m < 4; ++m)
            A[m] = *(const v8s*)&sXQ[(16 * m + l15) * SXS + kt * 32 + quad * 8];
#pragma unroll
        for (int jj = 0; jj < 3; ++jj) {
            v8s B = *(const v8s*)&WqT[(size_t)((3 * w + jj) * 16 + l15) * WPAD +
                                      kt * 32 + quad * 8];
#pragma unroll
            for (int m = 0; m < 4; ++m)
                qacc[jj * 4 + m] = __builtin_amdgcn_mfma_f32_16x16x32_bf16(
                    A[m], B, qacc[jj * 4 + m], 0, 0, 0);
        }
    }
    __syncthreads();   // all waves done READING gs before Q overwrites it
#pragma unroll
    for (int jj = 0; jj < 3; ++jj) {
        int j = (3 * w + jj) * 16 + l15;
        if (j < DIM) {
            int h = j / HD;
            int pos = j + 2 * h;          // 32-padded head-slab column
            float bqj = bq[j];
#pragma unroll
            for (int m = 0; m < 4; ++m)
#pragma unroll
                for (int r = 0; r < 4; ++r) {
                    float v = (qacc[jj * 4 + m][r] + bqj) * SCALE;
                    sXQ[(16 * m + quad * 4 + r) * SXS + pos] =
                        (u16)cvt_pk_bf16(v, v);
                }
        }
    }
    // zero Q pad cols d=30,31 of every head slab
    for (int i = tid; i < TQ * 12; i += 256) {
        int row = i / 12, c = i - row * 12;
        sXQ[row * SXS + (c >> 1) * 32 + 30 + (c & 1)] = 0;
    }

    // ---- prologue stages: K0, K1, V0 ----
    {
        const u16* kg0 = Kb + (size_t)(b * HEADS + 0) * KB_STRIDE;
        const u16* kg1 = Kb + (size_t)(b * HEADS + 1) * KB_STRIDE;
        const u16* vg0 = VbT + (size_t)(b * HEADS + 0) * VB_STRIDE;
        for (int i = tid; i < 576; i += 256) gload_lds16(kg0 + i * 8, sK2 + i * 8);
        for (int i = tid; i < 576; i += 256)
            gload_lds16(kg1 + i * 8, sK2 + NKEY * KROW + i * 8);
        for (int i = tid; i < 608; i += 256) gload_lds16(vg0 + i * 8, sV + i * 8);
    }
    __syncthreads();   // Q ready + K0/K1/V0 staged

    // ---- per-head attention ----
    for (int h = 0; h < HEADS; ++h) {
        const u16* sKc = sK2 + (h & 1) * (NKEY * KROW);

        // bias loads (per-wave, plain; consumed ~QK start)
        const u16* bgt = biasCT +
            ((size_t)((h * 144 + (qt * 4 + w)) * 9) * 256) + lane * 4;
        uint2 bb[9];
#pragma unroll
        for (int t = 0; t < 9; ++t) bb[t] = *(const uint2*)(bgt + t * 256);

        // Q B-fragment: own q rows (16w+l15), this head's 32-col slab
        v8s qa = *(const v8s*)&sXQ[(16 * w + l15) * SXS + h * 32 + quad * 8];

        // S^T = K · Q^T + bias^T ; C tile t: rowpos n'=16t+quad*4+r (key
        // sigma(n')), col q=16w+l15. sK read un-swizzles: group quad^(l15&3).
        v4f la[9];
#pragma unroll
        for (int t = 0; t < 9; ++t) {
            la[t][0] = bf2f((u16)(bb[t].x & 0xffff));
            la[t][1] = bf2f((u16)(bb[t].x >> 16));
            la[t][2] = bf2f((u16)(bb[t].y & 0xffff));
            la[t][3] = bf2f((u16)(bb[t].y >> 16));
        }
#pragma unroll
        for (int t = 0; t < 9; ++t) {
            v8s kb = *(const v8s*)&sKc[(16 * t + l15) * KROW +
                                       ((quad ^ (l15 & 3)) << 3)];
            la[t] = __builtin_amdgcn_mfma_f32_16x16x32_bf16(kb, qa, la[t], 0, 0, 0);
        }

        // softmax (exp2 domain), TREE reductions (R8: depth ~6 vs 36 serial)
        float mt[9];
#pragma unroll
        for (int t = 0; t < 9; ++t)
            mt[t] = fmaxf(fmaxf(la[t][0], la[t][1]), fmaxf(la[t][2], la[t][3]));
        float m = fmaxf(fmaxf(fmaxf(fmaxf(mt[0], mt[1]), fmaxf(mt[2], mt[3])),
                              fmaxf(fmaxf(mt[4], mt[5]), fmaxf(mt[6], mt[7]))),
                        mt[8]);
        m = fmaxf(m, __shfl_xor(m, 16));
        m = fmaxf(m, __shfl_xor(m, 32));
        float st[9];
#pragma unroll
        for (int t = 0; t < 9; ++t) {
#pragma unroll
            for (int r = 0; r < 4; ++r)
                la[t][r] = __builtin_amdgcn_exp2f(la[t][r] - m);
            st[t] = (la[t][0] + la[t][1]) + (la[t][2] + la[t][3]);
        }
        float s = (((st[0] + st[1]) + (st[2] + st[3])) +
                   ((st[4] + st[5]) + (st[6] + st[7]))) + st[8];
        s += __shfl_xor(s, 16);
        s += __shfl_xor(s, 32);
        float inv = 1.f / s;   // applied to x outputs, not to P

        // pack P (UNNORMALIZED) rows to bf16 dwords, kept in registers
        unsigned sd0[9], sd1[9];
#pragma unroll
        for (int t = 0; t < 9; ++t) {
            sd0[t] = cvt_pk_bf16(la[t][0], la[t][1]);
            sd1[t] = cvt_pk_bf16(la[t][2], la[t][3]);
        }

        __syncthreads();   // barA: V(h)/K(h+1) stages drained; QK(h) done

        // x^T = V^T · P^T : A = V^T rows from sV (lane=d), B = P^T built
        // IN-REGISTER: sigma makes the needed exchange exactly
        // swap(lane-bit5, reg-bit) = v_permlane32_swap_b32 per dword pair.
        v4f x0 = (v4f){0.f, 0.f, 0.f, 0.f}, x1 = x0;
#pragma unroll
        for (int kt = 0; kt < 5; ++kt) {
            unsigned d0, d1, d2, d3;
            if (kt < 4) {
                d0 = sd0[2 * kt];     d1 = sd1[2 * kt];
                d2 = sd0[2 * kt + 1]; d3 = sd1[2 * kt + 1];
            } else {
                d0 = sd0[8]; d1 = sd1[8]; d2 = 0u; d3 = 0u;
            }
            asm("v_permlane32_swap_b32 %0, %1" : "+v"(d0), "+v"(d2));
            asm("v_permlane32_swap_b32 %0, %1" : "+v"(d1), "+v"(d3));
            union { unsigned u[4]; v8s v; } pu;
            pu.u[0] = d0; pu.u[1] = d1; pu.u[2] = d2; pu.u[3] = d3;
            int co = kt * 32 + quad * 8;
            co = (co < NKEY) ? co : 0;       // pa is zero there (kt=4,q>=2)
            v8s a0 = *(const v8s*)&sV[l15 * VROW + co];
            v8s a1 = *(const v8s*)&sV[(16 + l15) * VROW + co];
            x0 = __builtin_amdgcn_mfma_f32_16x16x32_bf16(a0, pu.v, x0, 0, 0, 0);
            x1 = __builtin_amdgcn_mfma_f32_16x16x32_bf16(a1, pu.v, x1, 0, 0, 0);
        }
        // x^T C tile -> dead Q slab h; normalize by inv here (8 muls).
        v4f y0, y1;
#pragma unroll
        for (int r = 0; r < 4; ++r) { y0[r] = x0[r] * inv; y1[r] = x1[r] * inv; }
        *(uint2*)&sXQ[(16 * w + l15) * SXS + h * 32 + quad * 4]      = pack4(y0);
        *(uint2*)&sXQ[(16 * w + l15) * SXS + h * 32 + 16 + quad * 4] = pack4(y1);

        if (h < HEADS - 1) {
            __syncthreads();   // barB: all waves done PV(h) reading sV
            if (h + 2 < HEADS) {   // stage K(h+2) into the buffer QK(h) used
                const u16* kg = Kb + (size_t)(b * HEADS + h + 2) * KB_STRIDE;
                u16* dst = sK2 + (h & 1) * (NKEY * KROW);
                for (int i = tid; i < 576; i += 256)
                    gload_lds16(kg + i * 8, dst + i * 8);
            }
            {                      // stage V(h+1)
                const u16* vg = VbT + (size_t)(b * HEADS + h + 1) * VB_STRIDE;
                for (int i = tid; i < 608; i += 256)
                    gload_lds16(vg + i * 8, sV + i * 8);
            }
        }
    }
    __syncthreads();   // x rows are read cross-wave by out-proj

    // ---- out-proj: out = x @ Wp + bp ----
    {
        v4f acc[12];
#pragma unroll
        for (int i = 0; i < 12; ++i) acc[i] = (v4f){0.f, 0.f, 0.f, 0.f};
        for (int kt = 0; kt < 6; ++kt) {
            v8s A[4];
#pragma unroll
            for (int m = 0; m < 4; ++m)
                A[m] = *(const v8s*)&sXQ[(16 * m + l15) * SXS + kt * 32 + quad * 8];
#pragma unroll
            for (int jj = 0; jj < 3; ++jj) {
                v8s B = *(const v8s*)&WpT[(size_t)((3 * w + jj) * 16 + l15) * WPAD +
                                          kt * 32 + quad * 8];
#pragma unroll
                for (int m = 0; m < 4; ++m)
                    acc[jj * 4 + m] = __builtin_amdgcn_mfma_f32_16x16x32_bf16(
                        A[m], B, acc[jj * 4 + m], 0, 0, 0);
            }
        }
#pragma unroll
        for (int jj = 0; jj < 3; ++jj) {
            int j = (3 * w + jj) * 16 + l15;
            if (j < DIM) {
                float bpj = bp[j];
#pragma unroll
                for (int m = 0; m < 4; ++m)
#pragma unroll
                    for (int r = 0; r < 4; ++r)
                        out[(size_t)(b * NGS + q0 + 16 * m + quad * 4 + r) * DIM + j] =
                            acc[jj * 4 + m][r] + bpj;
            }
        }
    }
}

// ---------------------------------------------------------------------------
extern "C" void kernel_launch(void* const* d_in, const int* in_sizes, int n_in,
                              void* d_out, int out_size, void* d_ws, size_t ws_size,
                              hipStream_t stream) {
    const float* gs    = (const float*)d_in[0];
    const float* feat  = (const float*)d_in[1];
    const float* Wq    = (const float*)d_in[2];
    const float* bq    = (const float*)d_in[3];
    const float* Wk    = (const float*)d_in[4];
    const float* bk    = (const float*)d_in[5];
    const float* Wv    = (const float*)d_in[6];
    const float* bv    = (const float*)d_in[7];
    const float* Wp    = (const float*)d_in[8];
    const float* bp    = (const float*)d_in[9];
    const float* table = (const float*)d_in[10];
    const int*   rpi   = (const int*)d_in[11];
    float* out = (float*)d_out;

    // ws layout (u16 units): WqT | WpT | Kb | VbT | biasCT
    u16* WqT    = (u16*)d_ws;
    u16* WpT    = WqT + WPAD * WPAD;
    u16* Kb     = WpT + WPAD * WPAD;
    u16* VbT    = Kb  + (size_t)BATCH * HEADS * KB_STRIDE;
    u16* biasCT = VbT + (size_t)BATCH * HEADS * VB_STRIDE;

    // zero K pads (swizzled d=30,31 slots) and V pads: MFMA reads them
    size_t zero_bytes = (size_t)BATCH * HEADS * (KB_STRIDE + VB_STRIDE) * sizeof(u16);
    hipMemsetAsync(Kb, 0, zero_bytes, stream);

    wt_prep_kernel<<<dim3(2 * WPAD * WPAD / 256), dim3(256), 0, stream>>>(Wq, Wp, WqT, WpT);
    gather_bias_kernel<<<dim3(HEADS * 144 * 9 * 64 / 256), dim3(256), 0, stream>>>(
        table, rpi, biasCT);
    kv_proj_kernel<<<dim3(BATCH * 9), dim3(256), 0, stream>>>(feat, Wk, bk, Wv, bv, Kb, VbT);
    attn_kernel<<<dim3(BATCH * QT), dim3(256), 0, stream>>>(
        gs, WqT, bq, WpT, bp, Kb, VbT, biasCT, out);
}